// Round 9
// baseline (2526.657 us; speedup 1.0000x reference)
//
#include <hip/hip_runtime.h>
#include <hip/hip_bf16.h>
#include <stdint.h>

#define S_ 64
#define B_ 64
#define E_ 512
#define H_ 512
#define V_ 32000
#define G4 2048   // 4*H
#define SB 4096   // S*B

// d_out row = 32000 fp32 = 64000 ushort; G0 (bf16) lives in the tail 2048
// ushorts of each row: G0(sb, d, c) at ushort index sb*64000 + 59904 + d*2048 + c.
#define OROW_US 64000
#define GTAIL_US 59904   // 29952 fp32 * 2

typedef __attribute__((ext_vector_type(8))) short short8;
typedef __attribute__((ext_vector_type(4))) float f32x4;
typedef __attribute__((ext_vector_type(4))) int i32x4;

static __device__ __forceinline__ unsigned short f2bf(float f) {
  unsigned u = __float_as_uint(f);
  u += 0x7fff + ((u >> 16) & 1);   // RNE
  return (unsigned short)(u >> 16);
}
static __device__ __forceinline__ float bf2f(unsigned short u) {
  return __uint_as_float((unsigned)u << 16);
}
static __device__ __forceinline__ float sigm(float x) {
  return 1.f / (1.f + expf(-x));
}

__device__ __forceinline__ void gload_lds16(const void* g, void* l) {
  __builtin_amdgcn_global_load_lds(
      (const __attribute__((address_space(1))) void*)g,
      (__attribute__((address_space(3))) void*)l, 16, 0, 0);
}

// coherent (device-visible) 16-byte store: write-through past the XCD L2
__device__ __forceinline__ void st128_sys(void* p, i32x4 v) {
  asm volatile("global_store_dwordx4 %0, %1, off sc0 sc1"
               :: "v"((unsigned long long)p), "v"(v) : "memory");
}
__device__ __forceinline__ void wait_vm0() {
  asm volatile("s_waitcnt vmcnt(0)" ::: "memory");
}

// relaxed spin until *c >= tgt (agent-scope atomic load bypasses XCD L2)
__device__ __forceinline__ void spin_ge(unsigned* c, unsigned tgt) {
  while (__hip_atomic_load(c, __ATOMIC_RELAXED, __HIP_MEMORY_SCOPE_AGENT) < tgt)
    __builtin_amdgcn_s_sleep(1);
}
__device__ __forceinline__ void spin_ge_slow(unsigned* c, unsigned tgt) {
  while (__hip_atomic_load(c, __ATOMIC_RELAXED, __HIP_MEMORY_SCOPE_AGENT) < tgt)
    __builtin_amdgcn_s_sleep(16);
}
__device__ __forceinline__ void arrive(unsigned* c) {
  __hip_atomic_fetch_add(c, 1u, __ATOMIC_RELAXED, __HIP_MEMORY_SCOPE_AGENT);
}

// counter slot index: per (step, dir, part), 256B apart
#define CIDX(t, d, p) ((((t) * 8) + ((d) * 4) + (p)) * 64)
#define CNT_BYTES (64 * 8 * 64 * 4)

__global__ void k_f2bf(const float* __restrict__ in, unsigned short* __restrict__ out, int n) {
  int i = blockIdx.x * blockDim.x + threadIdx.x;
  int stride = gridDim.x * blockDim.x;
  for (; i < n; i += stride) out[i] = f2bf(in[i]);
}

__global__ void k_addbias(const float* __restrict__ a, const float* __restrict__ b,
                          float* __restrict__ out, int n) {
  int i = blockIdx.x * blockDim.x + threadIdx.x;
  if (i < n) out[i] = a[i] + b[i];
}

__global__ void k_gather(const int* __restrict__ Y, const float* __restrict__ emb,
                         unsigned short* __restrict__ X) {
  int sb = blockIdx.x;
  int t = sb >> 6, b = sb & 63;
  int idx = (t == 0) ? Y[b * S_ + 1] : Y[b * S_ + t - 1];
  const float* src = emb + (size_t)idx * E_;
  unsigned short* dst = X + (size_t)sb * E_;
  for (int e = threadIdx.x; e < E_; e += blockDim.x) dst[e] = f2bf(src[e]);
}

__global__ void k_init_h(const float* __restrict__ hid,
                         unsigned short* __restrict__ h0i, unsigned short* __restrict__ h1i) {
  int i = blockIdx.x * blockDim.x + threadIdx.x;
  if (i >= 4 * B_ * H_) return;
  unsigned short v = f2bf(hid[i]);
  if (i < 2 * B_ * H_) h0i[i] = v;
  else h1i[i - 2 * B_ * H_] = v;
}

// ---------------- G0 GEMM: G0(sb, cc) = X[sb,:] @ wih0cat[cc,:]^T + b0[cc] ----------------
// writes bf16 into the d_out row tails (layout above). bm-major + XCD swizzle.
__global__ __launch_bounds__(256) void k_gemm_g0(
    const unsigned short* __restrict__ A, const unsigned short* __restrict__ B,
    const float* __restrict__ bias, unsigned short* __restrict__ C,
    int K, int nTM, int nwg) {
  __shared__ unsigned short Als[128 * 32];
  __shared__ unsigned short Bls[128 * 32];
  int tid = threadIdx.x;
  int o = blockIdx.x;
  int wg = (o & 7) * (nwg >> 3) + (o >> 3);
  int bm = wg % nTM, bn = wg / nTM;
  int w = tid >> 6, l = tid & 63;
  int wr = w >> 1, wc = w & 1;
  int lr = l & 15, hi = l >> 4;
  int c0 = w * 128 + l;
  int row0 = c0 >> 2, ks0 = (((c0 & 3) ^ (row0 & 3)) * 8);
  int c1 = c0 + 64;
  int row1 = c1 >> 2, ks1 = (((c1 & 3) ^ (row1 & 3)) * 8);
  const unsigned short* Ab = A + (size_t)(bm * 128) * K;
  const unsigned short* Bb = B + (size_t)(bn * 128) * K;
  unsigned short* AlsW = &Als[w * 1024];
  unsigned short* BlsW = &Bls[w * 1024];
  int co = ((hi ^ (lr & 3)) * 8);
  f32x4 acc[4][4] = {};
  for (int kk = 0; kk < K; kk += 32) {
    __syncthreads();
    gload_lds16(Ab + (size_t)row0 * K + kk + ks0, AlsW);
    gload_lds16(Ab + (size_t)row1 * K + kk + ks1, AlsW + 512);
    gload_lds16(Bb + (size_t)row0 * K + kk + ks0, BlsW);
    gload_lds16(Bb + (size_t)row1 * K + kk + ks1, BlsW + 512);
    __syncthreads();
    short8 af[4], bfr[4];
#pragma unroll
    for (int r = 0; r < 4; r++)
      af[r] = *(const short8*)&Als[(wr * 64 + r * 16 + lr) * 32 + co];
#pragma unroll
    for (int c4 = 0; c4 < 4; c4++)
      bfr[c4] = *(const short8*)&Bls[(wc * 64 + c4 * 16 + lr) * 32 + co];
#pragma unroll
    for (int r = 0; r < 4; r++)
#pragma unroll
      for (int c4 = 0; c4 < 4; c4++)
        acc[r][c4] = __builtin_amdgcn_mfma_f32_16x16x32_bf16(af[r], bfr[c4], acc[r][c4], 0, 0, 0);
  }
  int rbase = bm * 128 + wr * 64 + hi * 4;
  int cbase = bn * 128 + wc * 64 + lr;
#pragma unroll
  for (int r = 0; r < 4; r++) {
#pragma unroll
    for (int c4 = 0; c4 < 4; c4++) {
      int cc = cbase + c4 * 16;
      float bv = bias[cc];
#pragma unroll
      for (int j = 0; j < 4; j++) {
        int rr = rbase + r * 16 + j;
        C[(size_t)rr * OROW_US + GTAIL_US + cc] = f2bf(acc[r][c4][j] + bv);
      }
    }
  }
}

// ---------------- MEGA kernel: recurrence (192 blocks) + projection (64 blocks) ----------------
// blocks [0,64): layer 0; [64,192): layer 1 (as R8, flags cnt0/cnt1);
// blocks [192,256): projection out[b*64+t, v] = O1[t*64+b,:] @ fcw^T + fcb,
//   gated per t-pair on cnt1; v-panels >= 234 (cols >= 29952, the G0 tail
//   region) deferred until cnt1[63] (l1 done => l0 done reading G0).
#define LDW0 520    // l0: 64 rows x (512+8)
#define LDW1 1544   // l1: 32 rows x (1536+8)

__global__ __launch_bounds__(256) void k_mega(
    const unsigned short* __restrict__ h0i,   // (2,B,H) bf16
    const unsigned short* __restrict__ h1i,   // (2,B,H) bf16
    const float* __restrict__ cell,           // (4,B,H) fp32
    const unsigned short* __restrict__ whh0,  // (2,2048,512) bf16
    const unsigned short* __restrict__ wih1,  // (2,2048,1024) bf16
    const unsigned short* __restrict__ whh1,  // (2,2048,512) bf16
    const float* __restrict__ b1s,            // (2,2048) fp32
    float* __restrict__ dout,                 // output + G0 tails
    const unsigned short* __restrict__ fcwb,  // (V,1024) bf16
    const float* __restrict__ fcb,            // (V,) fp32
    unsigned short* __restrict__ H0,          // (SB,1024) bf16
    unsigned short* __restrict__ O1,          // (SB,1024) bf16
    unsigned* __restrict__ cnt0, unsigned* __restrict__ cnt1) {
  __shared__ unsigned short SM[32 * LDW1];
  __shared__ __align__(16) unsigned short HS[64 * 16];
  int tid = threadIdx.x;
  int w = tid >> 6, l = tid & 63;
  int lr = l & 15, hi = l >> 4;
  const unsigned short* G0u = (const unsigned short*)dout;

  if (blockIdx.x < 64) {
    // ================= LAYER 0 =================
    int d = blockIdx.x >> 5, jt = blockIdx.x & 31;
    const unsigned short* Wd = whh0 + (size_t)d * (G4 * H_);
    for (int c = tid; c < 64 * 64; c += 256) {
      int row = c >> 6, ck = c & 63;
      int g = row >> 4, r16 = row & 15;
      *(int4*)&SM[row * LDW0 + ck * 8] =
          *(const int4*)&Wd[(size_t)(g * H_ + jt * 16 + r16) * H_ + ck * 8];
    }
    int j = jt * 16 + lr;
    int b0 = w * 16 + hi * 4;
    f32x4 creg;
    {
      const float* cd = cell + (size_t)d * (B_ * H_);
#pragma unroll
      for (int jj = 0; jj < 4; jj++) creg[jj] = cd[(size_t)(b0 + jj) * H_ + j];
    }
    __syncthreads();
    float gv[4][4];
    auto preloadG = [&](int t) {
#pragma unroll
      for (int jj = 0; jj < 4; jj++) {
        const unsigned short* Gb =
            G0u + (size_t)(t * B_ + b0 + jj) * OROW_US + GTAIL_US + d * 2048 + j;
#pragma unroll
        for (int g = 0; g < 4; g++) gv[g][jj] = bf2f(Gb[g * 512]);
      }
    };
    preloadG(0);
    for (int t = 0; t < S_; ++t) {
      if (t >= 1) {
        if (tid < 4) spin_ge(&cnt0[CIDX(t - 1, d, tid)], 8);
        __syncthreads();
      }
      const unsigned short* hp = (t == 0) ? h0i + (size_t)d * (B_ * H_)
                                          : H0 + (size_t)(t - 1) * B_ * 1024 + d * 512;
      size_t hstr = (t == 0) ? (size_t)H_ : 1024;
      const unsigned short* arow = hp + (size_t)(w * 16 + lr) * hstr + hi * 8;
      f32x4 acc[4] = {};
#pragma unroll
      for (int ki = 0; ki < 16; ki++) {
        short8 a = *(const short8*)&arow[ki * 32];
#pragma unroll
        for (int g = 0; g < 4; g++) {
          short8 bfr = *(const short8*)&SM[(g * 16 + lr) * LDW0 + ki * 32 + hi * 8];
          acc[g] = __builtin_amdgcn_mfma_f32_16x16x32_bf16(a, bfr, acc[g], 0, 0, 0);
        }
      }
#pragma unroll
      for (int jj = 0; jj < 4; jj++) {
        float gi = acc[0][jj] + gv[0][jj];
        float gf = acc[1][jj] + gv[1][jj];
        float gg = acc[2][jj] + gv[2][jj];
        float go = acc[3][jj] + gv[3][jj];
        float c = sigm(gf) * creg[jj] + sigm(gi) * tanhf(gg);
        creg[jj] = c;
        HS[(b0 + jj) * 16 + lr] = f2bf(sigm(go) * tanhf(c));
      }
      __syncthreads();
      unsigned short* Ho = H0 + (size_t)t * B_ * 1024 + d * 512 + jt * 16;
      if (tid < 128) {
        int r = tid >> 1, half = tid & 1;
        i32x4 v = *(const i32x4*)&HS[r * 16 + half * 8];
        st128_sys(&Ho[(size_t)r * 1024 + half * 8], v);
      }
      wait_vm0();
      __syncthreads();
      if (tid == 0) arrive(&cnt0[CIDX(t, d, jt & 3)]);
      if (t + 1 < S_) preloadG(t + 1);
    }
  } else if (blockIdx.x < 192) {
    // ================= LAYER 1 (pipelined) =================
    int idx = blockIdx.x - 64;
    int d = idx >> 6, jt8 = idx & 63;
    int j0 = jt8 * 8;
    {
      const unsigned short* Wih = wih1 + (size_t)d * (G4 * 1024);
      const unsigned short* Whh = whh1 + (size_t)d * (G4 * H_);
      for (int c = tid; c < 32 * 192; c += 256) {
        int r = c / 192, ck = c - r * 192;
        int g = r >> 3, jc = r & 7;
        const unsigned short* src =
            (ck < 128) ? Wih + (size_t)(g * H_ + j0 + jc) * 1024 + ck * 8
                       : Whh + (size_t)(g * H_ + j0 + jc) * H_ + (ck - 128) * 8;
        *(int4*)&SM[r * LDW1 + ck * 8] = *(const int4*)src;
      }
    }
    int j = j0 + (lr & 7);
    const float* b1d = b1s + d * G4;
    float bi_ = b1d[j], bf_ = b1d[512 + j], bg_ = b1d[1024 + j], bo_ = b1d[1536 + j];
    int b0 = w * 16 + hi * 4;
    f32x4 creg = {};
    if (lr < 8) {
      const float* cd = cell + (size_t)(2 + d) * (B_ * H_);
#pragma unroll
      for (int jj = 0; jj < 4; jj++) creg[jj] = cd[(size_t)(b0 + jj) * H_ + j];
    }
    __syncthreads();

    f32x4 acc0, acc1;
    {
      if (tid < 8) spin_ge(&cnt0[CIDX(0, 0, 0) + tid * 64], 8);
      __syncthreads();
      acc0 = {}; acc1 = {};
      const unsigned short* x1row = H0 + ((size_t)0 * B_ + w * 16 + lr) * 1024 + hi * 8;
#pragma unroll 8
      for (int ki = 0; ki < 32; ki++) {
        short8 a = *(const short8*)&x1row[ki * 32];
        short8 bA = *(const short8*)&SM[(size_t)lr * LDW1 + ki * 32 + hi * 8];
        short8 bB = *(const short8*)&SM[(size_t)(16 + lr) * LDW1 + ki * 32 + hi * 8];
        acc0 = __builtin_amdgcn_mfma_f32_16x16x32_bf16(a, bA, acc0, 0, 0, 0);
        acc1 = __builtin_amdgcn_mfma_f32_16x16x32_bf16(a, bB, acc1, 0, 0, 0);
      }
    }
    for (int t = 0; t < S_; ++t) {
      if (t >= 1) {
        if (tid < 4) spin_ge(&cnt1[CIDX(t - 1, d, tid)], 16);
        __syncthreads();
      }
      const unsigned short* hprev = (t == 0)
          ? h1i + (size_t)d * (B_ * H_) + (size_t)(w * 16 + lr) * H_ + hi * 8
          : O1 + ((size_t)(t - 1) * B_ + w * 16 + lr) * 1024 + d * 512 + hi * 8;
#pragma unroll 8
      for (int ki = 0; ki < 16; ki++) {
        short8 a = *(const short8*)&hprev[ki * 32];
        short8 bA = *(const short8*)&SM[(size_t)lr * LDW1 + 1024 + ki * 32 + hi * 8];
        short8 bB = *(const short8*)&SM[(size_t)(16 + lr) * LDW1 + 1024 + ki * 32 + hi * 8];
        acc0 = __builtin_amdgcn_mfma_f32_16x16x32_bf16(a, bA, acc0, 0, 0, 0);
        acc1 = __builtin_amdgcn_mfma_f32_16x16x32_bf16(a, bB, acc1, 0, 0, 0);
      }
      float pf[4], po[4];
#pragma unroll
      for (int jj = 0; jj < 4; jj++) {
        pf[jj] = __shfl_xor(acc0[jj], 8);
        po[jj] = __shfl_xor(acc1[jj], 8);
      }
      if (lr < 8) {
#pragma unroll
        for (int jj = 0; jj < 4; jj++) {
          float gi = acc0[jj] + bi_;
          float gf = pf[jj] + bf_;
          float gg = acc1[jj] + bg_;
          float go = po[jj] + bo_;
          float c = sigm(gf) * creg[jj] + sigm(gi) * tanhf(gg);
          creg[jj] = c;
          HS[(b0 + jj) * 8 + lr] = f2bf(sigm(go) * tanhf(c));
        }
      }
      __syncthreads();
      unsigned short* Oo = O1 + (size_t)t * B_ * 1024 + d * 512 + j0;
      if (tid < 64) {
        i32x4 v = *(const i32x4*)&HS[tid * 8];
        st128_sys(&Oo[(size_t)tid * 1024], v);
      }
      wait_vm0();
      __syncthreads();
      if (tid == 0) arrive(&cnt1[CIDX(t, d, jt8 & 3)]);
      if (t + 1 < S_) {
        if (tid < 8) spin_ge(&cnt0[CIDX(t + 1, 0, 0) + tid * 64], 8);
        __syncthreads();
        acc0 = {}; acc1 = {};
        const unsigned short* x1row =
            H0 + ((size_t)(t + 1) * B_ + w * 16 + lr) * 1024 + hi * 8;
#pragma unroll 8
        for (int ki = 0; ki < 32; ki++) {
          short8 a = *(const short8*)&x1row[ki * 32];
          short8 bA = *(const short8*)&SM[(size_t)lr * LDW1 + ki * 32 + hi * 8];
          short8 bB = *(const short8*)&SM[(size_t)(16 + lr) * LDW1 + ki * 32 + hi * 8];
          acc0 = __builtin_amdgcn_mfma_f32_16x16x32_bf16(a, bA, acc0, 0, 0, 0);
          acc1 = __builtin_amdgcn_mfma_f32_16x16x32_bf16(a, bB, acc1, 0, 0, 0);
        }
      }
    }
  } else {
    // ================= PROJECTION (64 blocks) =================
    int i = blockIdx.x - 192;   // 0..63
    unsigned short* Als = SM;           // 128*32
    unsigned short* Bls = SM + 4096;    // 128*32
    int wr = w >> 1, wc = w & 1;
    int c0 = w * 128 + l;
    int row0 = c0 >> 2, ks0 = (((c0 & 3) ^ (row0 & 3)) * 8);
    int c1 = c0 + 64;
    int row1 = c1 >> 2, ks1 = (((c1 & 3) ^ (row1 & 3)) * 8);
    int co = ((hi ^ (lr & 3)) * 8);
    auto tile = [&](int bm, int bn) {
      const unsigned short* Ab = O1 + (size_t)(bm * 128) * 1024;
      const unsigned short* Bb = fcwb + (size_t)(bn * 128) * 1024;
      unsigned short* AlsW = &Als[w * 1024];
      unsigned short* BlsW = &Bls[w * 1024];
      f32x4 acc[4][4] = {};
      for (int kk = 0; kk < 1024; kk += 32) {
        __syncthreads();
        gload_lds16(Ab + (size_t)row0 * 1024 + kk + ks0, AlsW);
        gload_lds16(Ab + (size_t)row1 * 1024 + kk + ks1, AlsW + 512);
        gload_lds16(Bb + (size_t)row0 * 1024 + kk + ks0, BlsW);
        gload_lds16(Bb + (size_t)row1 * 1024 + kk + ks1, BlsW + 512);
        __syncthreads();
        short8 af[4], bfr[4];
#pragma unroll
        for (int r = 0; r < 4; r++)
          af[r] = *(const short8*)&Als[(wr * 64 + r * 16 + lr) * 32 + co];
#pragma unroll
        for (int c4 = 0; c4 < 4; c4++)
          bfr[c4] = *(const short8*)&Bls[(wc * 64 + c4 * 16 + lr) * 32 + co];
#pragma unroll
        for (int r = 0; r < 4; r++)
#pragma unroll
          for (int c4 = 0; c4 < 4; c4++)
            acc[r][c4] = __builtin_amdgcn_mfma_f32_16x16x32_bf16(af[r], bfr[c4], acc[r][c4], 0, 0, 0);
      }
      int rbase = bm * 128 + wr * 64 + hi * 4;
      int cbase = bn * 128 + wc * 64 + lr;
#pragma unroll
      for (int r = 0; r < 4; r++) {
#pragma unroll
        for (int c4 = 0; c4 < 4; c4++) {
          int cc = cbase + c4 * 16;
          float bv = fcb[cc];
#pragma unroll
          for (int j = 0; j < 4; j++) {
            int rr = rbase + r * 16 + j;
            size_t orow = (size_t)((rr & 63) * 64 + (rr >> 6));
            __builtin_nontemporal_store(acc[r][c4][j] + bv, &dout[orow * V_ + cc]);
          }
        }
      }
    };
    // phase 1: frontier-chasing sweep over t-pairs, non-tail v-panels
    for (int bm = 0; bm < 32; ++bm) {
      if (tid < 16) {
        int t = bm * 2 + (tid >> 3), dd = (tid >> 2) & 1, p = tid & 3;
        spin_ge_slow(&cnt1[CIDX(t, dd, p)], 16);
      }
      __syncthreads();
      for (int bn = i; bn < 234; bn += 64) tile(bm, bn);
    }
    // phase 2: tail v-panels (G0 region) after l1 fully done (implies l0 done)
    if (tid < 8) spin_ge_slow(&cnt1[CIDX(63, tid >> 2, tid & 3)], 16);
    __syncthreads();
    for (int k = i; k < 512; k += 64) tile(k >> 4, 234 + (k & 15));
  }
}

extern "C" void kernel_launch(void* const* d_in, const int* in_sizes, int n_in,
                              void* d_out, int out_size, void* d_ws, size_t ws_size,
                              hipStream_t stream) {
  const float* hidden = (const float*)d_in[0];
  const float* cell   = (const float*)d_in[1];
  const int*   Y      = (const int*)d_in[2];
  const float* emb    = (const float*)d_in[3];
  const float* wih0   = (const float*)d_in[4];
  const float* whh0   = (const float*)d_in[5];
  const float* bih0   = (const float*)d_in[6];
  const float* bhh0   = (const float*)d_in[7];
  const float* wih1   = (const float*)d_in[8];
  const float* whh1   = (const float*)d_in[9];
  const float* bih1   = (const float*)d_in[10];
  const float* bhh1   = (const float*)d_in[11];
  const float* fcw    = (const float*)d_in[12];
  const float* fcb    = (const float*)d_in[13];

  char* ws = (char*)d_ws;
  size_t off = 0;
  auto alloc = [&](size_t bytes) {
    void* p = ws + off;
    off += (bytes + 255) & ~(size_t)255;
    return p;
  };
  unsigned short* wih0b = (unsigned short*)alloc((size_t)2 * G4 * E_ * 2);
  unsigned short* whh0b = (unsigned short*)alloc((size_t)2 * G4 * H_ * 2);
  unsigned short* wih1b = (unsigned short*)alloc((size_t)2 * G4 * 1024 * 2);
  unsigned short* whh1b = (unsigned short*)alloc((size_t)2 * G4 * H_ * 2);
  unsigned short* fcwb  = (unsigned short*)alloc((size_t)V_ * 1024 * 2);
  unsigned short* Xb    = (unsigned short*)alloc((size_t)SB * E_ * 2);
  unsigned short* H0    = (unsigned short*)alloc((size_t)SB * 1024 * 2);
  unsigned short* O1    = (unsigned short*)alloc((size_t)SB * 1024 * 2);
  unsigned short* h0i   = (unsigned short*)alloc((size_t)2 * B_ * H_ * 2);
  unsigned short* h1i   = (unsigned short*)alloc((size_t)2 * B_ * H_ * 2);
  float* b0s = (float*)alloc((size_t)2 * G4 * 4);
  float* b1s = (float*)alloc((size_t)2 * G4 * 4);
  unsigned* cnt0 = (unsigned*)alloc(CNT_BYTES);
  unsigned* cnt1 = (unsigned*)alloc(CNT_BYTES);
  (void)ws_size;

  // --- prep ---
  k_f2bf<<<2048, 256, 0, stream>>>(wih0, wih0b, 2 * G4 * E_);
  k_f2bf<<<2048, 256, 0, stream>>>(whh0, whh0b, 2 * G4 * H_);
  k_f2bf<<<2048, 256, 0, stream>>>(wih1, wih1b, 2 * G4 * 1024);
  k_f2bf<<<2048, 256, 0, stream>>>(whh1, whh1b, 2 * G4 * H_);
  k_f2bf<<<4096, 256, 0, stream>>>(fcw, fcwb, V_ * 1024);
  k_addbias<<<16, 256, 0, stream>>>(bih0, bhh0, b0s, 2 * G4);
  k_addbias<<<16, 256, 0, stream>>>(bih1, bhh1, b1s, 2 * G4);
  k_gather<<<SB, 256, 0, stream>>>(Y, emb, Xb);
  k_init_h<<<512, 256, 0, stream>>>(hidden, h0i, h1i);
  (void)hipMemsetAsync(cnt0, 0, CNT_BYTES, stream);
  (void)hipMemsetAsync(cnt1, 0, CNT_BYTES, stream);

  // --- layer-0 input gates -> bf16 G0 in d_out row tails ---
  k_gemm_g0<<<1024, 256, 0, stream>>>(Xb, wih0b, b0s, (unsigned short*)d_out,
                                      E_, SB / 128, 1024);

  // --- mega: persistent recurrence + overlapped projection ---
  k_mega<<<256, 256, 0, stream>>>(h0i, h1i, cell, whh0b, wih1b, whh1b, b1s,
                                  (float*)d_out, fcwb, fcb, H0, O1, cnt0, cnt1);
}

// Round 10
// 1818.532 us; speedup vs baseline: 1.3894x; 1.3894x over previous
//
#include <hip/hip_runtime.h>
#include <hip/hip_bf16.h>
#include <stdint.h>

#define S_ 64
#define B_ 64
#define E_ 512
#define H_ 512
#define V_ 32000
#define G4 2048   // 4*H
#define SB 4096   // S*B

// d_out row = 32000 fp32 = 64000 ushort; G0 (bf16) lives in the tail 2048
// ushorts of each row: G0(sb, d, c) at ushort index sb*64000 + 59904 + d*2048 + c.
#define OROW_US 64000
#define GTAIL_US 59904   // 29952 fp32 * 2

typedef __attribute__((ext_vector_type(8))) short short8;
typedef __attribute__((ext_vector_type(4))) float f32x4;
typedef __attribute__((ext_vector_type(4))) int i32x4;

static __device__ __forceinline__ unsigned short f2bf(float f) {
  unsigned u = __float_as_uint(f);
  u += 0x7fff + ((u >> 16) & 1);   // RNE
  return (unsigned short)(u >> 16);
}
static __device__ __forceinline__ float bf2f(unsigned short u) {
  return __uint_as_float((unsigned)u << 16);
}
static __device__ __forceinline__ float sigm(float x) {
  return 1.f / (1.f + expf(-x));
}

__device__ __forceinline__ void gload_lds16(const void* g, void* l) {
  __builtin_amdgcn_global_load_lds(
      (const __attribute__((address_space(1))) void*)g,
      (__attribute__((address_space(3))) void*)l, 16, 0, 0);
}

// coherent (device-visible) 16-byte store: write-through past the XCD L2
__device__ __forceinline__ void st128_sys(void* p, i32x4 v) {
  asm volatile("global_store_dwordx4 %0, %1, off sc0 sc1"
               :: "v"((unsigned long long)p), "v"(v) : "memory");
}
__device__ __forceinline__ void wait_vm0() {
  asm volatile("s_waitcnt vmcnt(0)" ::: "memory");
}

__device__ __forceinline__ void spin_ge(unsigned* c, unsigned tgt) {
  while (__hip_atomic_load(c, __ATOMIC_RELAXED, __HIP_MEMORY_SCOPE_AGENT) < tgt)
    __builtin_amdgcn_s_sleep(1);
}
__device__ __forceinline__ void spin_ge_slow(unsigned* c, unsigned tgt) {
  while (__hip_atomic_load(c, __ATOMIC_RELAXED, __HIP_MEMORY_SCOPE_AGENT) < tgt)
    __builtin_amdgcn_s_sleep(64);
}
__device__ __forceinline__ void arrive(unsigned* c) {
  __hip_atomic_fetch_add(c, 1u, __ATOMIC_RELAXED, __HIP_MEMORY_SCOPE_AGENT);
}

// fine-grain counter slot: per (step, dir, part), 256B apart (R8-proven)
#define CIDX(t, d, p) ((((t) * 8) + ((d) * 4) + (p)) * 64)
#define CNT_BYTES (64 * 8 * 64 * 4)
#define AGG_BYTES (64 * 16 * 4)   // per-t aggregate, 64B apart

__global__ void k_f2bf(const float* __restrict__ in, unsigned short* __restrict__ out, int n) {
  int i = blockIdx.x * blockDim.x + threadIdx.x;
  int stride = gridDim.x * blockDim.x;
  for (; i < n; i += stride) out[i] = f2bf(in[i]);
}

__global__ void k_addbias(const float* __restrict__ a, const float* __restrict__ b,
                          float* __restrict__ out, int n) {
  int i = blockIdx.x * blockDim.x + threadIdx.x;
  if (i < n) out[i] = a[i] + b[i];
}

__global__ void k_gather(const int* __restrict__ Y, const float* __restrict__ emb,
                         unsigned short* __restrict__ X) {
  int sb = blockIdx.x;
  int t = sb >> 6, b = sb & 63;
  int idx = (t == 0) ? Y[b * S_ + 1] : Y[b * S_ + t - 1];
  const float* src = emb + (size_t)idx * E_;
  unsigned short* dst = X + (size_t)sb * E_;
  for (int e = threadIdx.x; e < E_; e += blockDim.x) dst[e] = f2bf(src[e]);
}

__global__ void k_init_h(const float* __restrict__ hid,
                         unsigned short* __restrict__ h0i, unsigned short* __restrict__ h1i) {
  int i = blockIdx.x * blockDim.x + threadIdx.x;
  if (i >= 4 * B_ * H_) return;
  unsigned short v = f2bf(hid[i]);
  if (i < 2 * B_ * H_) h0i[i] = v;
  else h1i[i - 2 * B_ * H_] = v;
}

// ---------------- G0 GEMM: bf16 into d_out row tails ----------------
__global__ __launch_bounds__(256) void k_gemm_g0(
    const unsigned short* __restrict__ A, const unsigned short* __restrict__ B,
    const float* __restrict__ bias, unsigned short* __restrict__ C,
    int K, int nTM, int nwg) {
  __shared__ unsigned short Als[128 * 32];
  __shared__ unsigned short Bls[128 * 32];
  int tid = threadIdx.x;
  int o = blockIdx.x;
  int wg = (o & 7) * (nwg >> 3) + (o >> 3);
  int bm = wg % nTM, bn = wg / nTM;
  int w = tid >> 6, l = tid & 63;
  int wr = w >> 1, wc = w & 1;
  int lr = l & 15, hi = l >> 4;
  int c0 = w * 128 + l;
  int row0 = c0 >> 2, ks0 = (((c0 & 3) ^ (row0 & 3)) * 8);
  int c1 = c0 + 64;
  int row1 = c1 >> 2, ks1 = (((c1 & 3) ^ (row1 & 3)) * 8);
  const unsigned short* Ab = A + (size_t)(bm * 128) * K;
  const unsigned short* Bb = B + (size_t)(bn * 128) * K;
  unsigned short* AlsW = &Als[w * 1024];
  unsigned short* BlsW = &Bls[w * 1024];
  int co = ((hi ^ (lr & 3)) * 8);
  f32x4 acc[4][4] = {};
  for (int kk = 0; kk < K; kk += 32) {
    __syncthreads();
    gload_lds16(Ab + (size_t)row0 * K + kk + ks0, AlsW);
    gload_lds16(Ab + (size_t)row1 * K + kk + ks1, AlsW + 512);
    gload_lds16(Bb + (size_t)row0 * K + kk + ks0, BlsW);
    gload_lds16(Bb + (size_t)row1 * K + kk + ks1, BlsW + 512);
    __syncthreads();
    short8 af[4], bfr[4];
#pragma unroll
    for (int r = 0; r < 4; r++)
      af[r] = *(const short8*)&Als[(wr * 64 + r * 16 + lr) * 32 + co];
#pragma unroll
    for (int c4 = 0; c4 < 4; c4++)
      bfr[c4] = *(const short8*)&Bls[(wc * 64 + c4 * 16 + lr) * 32 + co];
#pragma unroll
    for (int r = 0; r < 4; r++)
#pragma unroll
      for (int c4 = 0; c4 < 4; c4++)
        acc[r][c4] = __builtin_amdgcn_mfma_f32_16x16x32_bf16(af[r], bfr[c4], acc[r][c4], 0, 0, 0);
  }
  int rbase = bm * 128 + wr * 64 + hi * 4;
  int cbase = bn * 128 + wc * 64 + lr;
#pragma unroll
  for (int r = 0; r < 4; r++) {
#pragma unroll
    for (int c4 = 0; c4 < 4; c4++) {
      int cc = cbase + c4 * 16;
      float bv = bias[cc];
#pragma unroll
      for (int j = 0; j < 4; j++) {
        int rr = rbase + r * 16 + j;
        C[(size_t)rr * OROW_US + GTAIL_US + cc] = f2bf(acc[r][c4][j] + bv);
      }
    }
  }
}

// ---------------- MEGA: recurrence (128 blocks) + projection (320 blocks) ----------------
// [0,64): layer 0 (d=blk>>5, jt=blk&31, 16 j-cols, whh0 in LDS, G0 from d_out tails)
// [64,128): layer 1 (d=idx>>5, jt=idx&31, 16 j-cols, whh1 in LDS, wih1 from GLOBAL
//           in the pipelined x1 phase; l0-style gate layout)
// [128,448): projection, 25 tiles each (l = p + 320k; bm=l/250, bn=l%250),
//           gated on agg1[t] (tgt 64); bn>=234 (G0-tail region) deferred to agg1[63].
// LDS 68.6KB + launch_bounds(256,2) => 2 blocks/CU => all 448 resident.
// Deadlock-free for ANY residency: rec waits only on rec; proj waits only on rec.
#define LDW0 520    // 64 rows x (512+8)

__global__ __launch_bounds__(256, 2) void k_mega(
    const unsigned short* __restrict__ h0i,   // (2,B,H) bf16
    const unsigned short* __restrict__ h1i,   // (2,B,H) bf16
    const float* __restrict__ cell,           // (4,B,H) fp32
    const unsigned short* __restrict__ whh0,  // (2,2048,512) bf16
    const unsigned short* __restrict__ wih1,  // (2,2048,1024) bf16
    const unsigned short* __restrict__ whh1,  // (2,2048,512) bf16
    const float* __restrict__ b1s,            // (2,2048) fp32
    float* __restrict__ dout,                 // output + G0 tails
    const unsigned short* __restrict__ fcwb,  // (V,1024) bf16
    const float* __restrict__ fcb,            // (V,) fp32
    unsigned short* __restrict__ H0,          // (SB,1024) bf16
    unsigned short* __restrict__ O1,          // (SB,1024) bf16
    unsigned* __restrict__ cnt0, unsigned* __restrict__ cnt1,
    unsigned* __restrict__ agg1) {            // 64 slots, 64B apart
  __shared__ unsigned short SM[64 * LDW0];
  __shared__ __align__(16) unsigned short HS[64 * 16];
  int tid = threadIdx.x;
  int w = tid >> 6, l = tid & 63;
  int lr = l & 15, hi = l >> 4;
  const unsigned short* G0u = (const unsigned short*)dout;

  if (blockIdx.x < 64) {
    // ================= LAYER 0 =================
    int d = blockIdx.x >> 5, jt = blockIdx.x & 31;
    const unsigned short* Wd = whh0 + (size_t)d * (G4 * H_);
    for (int c = tid; c < 64 * 64; c += 256) {
      int row = c >> 6, ck = c & 63;
      int g = row >> 4, r16 = row & 15;
      *(int4*)&SM[row * LDW0 + ck * 8] =
          *(const int4*)&Wd[(size_t)(g * H_ + jt * 16 + r16) * H_ + ck * 8];
    }
    int j = jt * 16 + lr;
    int b0 = w * 16 + hi * 4;
    f32x4 creg;
    {
      const float* cd = cell + (size_t)d * (B_ * H_);
#pragma unroll
      for (int jj = 0; jj < 4; jj++) creg[jj] = cd[(size_t)(b0 + jj) * H_ + j];
    }
    __syncthreads();
    float gv[4][4];
    auto preloadG = [&](int t) {
#pragma unroll
      for (int jj = 0; jj < 4; jj++) {
        const unsigned short* Gb =
            G0u + (size_t)(t * B_ + b0 + jj) * OROW_US + GTAIL_US + d * 2048 + j;
#pragma unroll
        for (int g = 0; g < 4; g++) gv[g][jj] = bf2f(Gb[g * 512]);
      }
    };
    preloadG(0);
    for (int t = 0; t < S_; ++t) {
      if (t >= 1) {
        if (tid < 4) spin_ge(&cnt0[CIDX(t - 1, d, tid)], 8);
        __syncthreads();
      }
      const unsigned short* hp = (t == 0) ? h0i + (size_t)d * (B_ * H_)
                                          : H0 + (size_t)(t - 1) * B_ * 1024 + d * 512;
      size_t hstr = (t == 0) ? (size_t)H_ : 1024;
      const unsigned short* arow = hp + (size_t)(w * 16 + lr) * hstr + hi * 8;
      f32x4 acc[4] = {};
#pragma unroll
      for (int ki = 0; ki < 16; ki++) {
        short8 a = *(const short8*)&arow[ki * 32];
#pragma unroll
        for (int g = 0; g < 4; g++) {
          short8 bfr = *(const short8*)&SM[(g * 16 + lr) * LDW0 + ki * 32 + hi * 8];
          acc[g] = __builtin_amdgcn_mfma_f32_16x16x32_bf16(a, bfr, acc[g], 0, 0, 0);
        }
      }
#pragma unroll
      for (int jj = 0; jj < 4; jj++) {
        float gi = acc[0][jj] + gv[0][jj];
        float gf = acc[1][jj] + gv[1][jj];
        float gg = acc[2][jj] + gv[2][jj];
        float go = acc[3][jj] + gv[3][jj];
        float c = sigm(gf) * creg[jj] + sigm(gi) * tanhf(gg);
        creg[jj] = c;
        HS[(b0 + jj) * 16 + lr] = f2bf(sigm(go) * tanhf(c));
      }
      __syncthreads();
      unsigned short* Ho = H0 + (size_t)t * B_ * 1024 + d * 512 + jt * 16;
      if (tid < 128) {
        int r = tid >> 1, half = tid & 1;
        i32x4 v = *(const i32x4*)&HS[r * 16 + half * 8];
        st128_sys(&Ho[(size_t)r * 1024 + half * 8], v);
      }
      wait_vm0();
      __syncthreads();
      if (tid == 0) arrive(&cnt0[CIDX(t, d, jt & 3)]);
      if (t + 1 < S_) preloadG(t + 1);
    }
  } else if (blockIdx.x < 128) {
    // ================= LAYER 1 (16 j-cols, whh in LDS, wih from global) =================
    int idx = blockIdx.x - 64;
    int d = idx >> 5, jt = idx & 31;
    const unsigned short* Wd = whh1 + (size_t)d * (G4 * H_);
    for (int c = tid; c < 64 * 64; c += 256) {
      int row = c >> 6, ck = c & 63;
      int g = row >> 4, r16 = row & 15;
      *(int4*)&SM[row * LDW0 + ck * 8] =
          *(const int4*)&Wd[(size_t)(g * H_ + jt * 16 + r16) * H_ + ck * 8];
    }
    int j = jt * 16 + lr;
    int b0 = w * 16 + hi * 4;
    const float* b1d = b1s + d * G4;
    float bi_[4];
#pragma unroll
    for (int g = 0; g < 4; g++) bi_[g] = b1d[g * 512 + j];
    f32x4 creg;
    {
      const float* cd = cell + (size_t)(2 + d) * (B_ * H_);
#pragma unroll
      for (int jj = 0; jj < 4; jj++) creg[jj] = cd[(size_t)(b0 + jj) * H_ + j];
    }
    __syncthreads();
    // global wih1 row bases for this thread's B fragments
    const unsigned short* Wg[4];
#pragma unroll
    for (int g = 0; g < 4; g++)
      Wg[g] = wih1 + (size_t)d * (G4 * 1024) + (size_t)(g * 512 + jt * 16 + lr) * 1024 + hi * 8;

    f32x4 acc[4];
    auto x1phase = [&](int t) {
      if (tid < 8) spin_ge(&cnt0[CIDX(t, 0, 0) + tid * 64], 8);
      __syncthreads();
#pragma unroll
      for (int g = 0; g < 4; g++) acc[g] = (f32x4){};
      const unsigned short* x1row = H0 + ((size_t)t * B_ + w * 16 + lr) * 1024 + hi * 8;
#pragma unroll 4
      for (int ki = 0; ki < 32; ki++) {
        short8 a = *(const short8*)&x1row[ki * 32];
#pragma unroll
        for (int g = 0; g < 4; g++) {
          short8 bfr = *(const short8*)&Wg[g][ki * 32];
          acc[g] = __builtin_amdgcn_mfma_f32_16x16x32_bf16(a, bfr, acc[g], 0, 0, 0);
        }
      }
    };
    x1phase(0);
    for (int t = 0; t < S_; ++t) {
      if (t >= 1) {
        if (tid < 4) spin_ge(&cnt1[CIDX(t - 1, d, tid)], 8);
        __syncthreads();
      }
      const unsigned short* hprev = (t == 0)
          ? h1i + (size_t)d * (B_ * H_) + (size_t)(w * 16 + lr) * H_ + hi * 8
          : O1 + ((size_t)(t - 1) * B_ + w * 16 + lr) * 1024 + d * 512 + hi * 8;
#pragma unroll
      for (int ki = 0; ki < 16; ki++) {
        short8 a = *(const short8*)&hprev[ki * 32];
#pragma unroll
        for (int g = 0; g < 4; g++) {
          short8 bfr = *(const short8*)&SM[(g * 16 + lr) * LDW0 + ki * 32 + hi * 8];
          acc[g] = __builtin_amdgcn_mfma_f32_16x16x32_bf16(a, bfr, acc[g], 0, 0, 0);
        }
      }
#pragma unroll
      for (int jj = 0; jj < 4; jj++) {
        float gi = acc[0][jj] + bi_[0];
        float gf = acc[1][jj] + bi_[1];
        float gg = acc[2][jj] + bi_[2];
        float go = acc[3][jj] + bi_[3];
        float c = sigm(gf) * creg[jj] + sigm(gi) * tanhf(gg);
        creg[jj] = c;
        HS[(b0 + jj) * 16 + lr] = f2bf(sigm(go) * tanhf(c));
      }
      __syncthreads();
      unsigned short* Oo = O1 + (size_t)t * B_ * 1024 + d * 512 + jt * 16;
      if (tid < 128) {
        int r = tid >> 1, half = tid & 1;
        i32x4 v = *(const i32x4*)&HS[r * 16 + half * 8];
        st128_sys(&Oo[(size_t)r * 1024 + half * 8], v);
      }
      wait_vm0();
      __syncthreads();
      if (tid == 0) arrive(&cnt1[CIDX(t, d, jt & 3)]);
      if (tid == 64) arrive(&agg1[t * 16]);
      if (t + 1 < S_) x1phase(t + 1);
    }
  } else {
    // ================= PROJECTION (320 blocks, 25 tiles each) =================
    int p = blockIdx.x - 128;
    unsigned short* Als = SM;
    unsigned short* Bls = SM + 4096;
    int wr = w >> 1, wc = w & 1;
    int c0 = w * 128 + l;
    int row0 = c0 >> 2, ks0 = (((c0 & 3) ^ (row0 & 3)) * 8);
    int c1 = c0 + 64;
    int row1 = c1 >> 2, ks1 = (((c1 & 3) ^ (row1 & 3)) * 8);
    int co = ((hi ^ (lr & 3)) * 8);
    auto tile = [&](int bm, int bn) {
      const unsigned short* Ab = O1 + (size_t)(bm * 128) * 1024;
      const unsigned short* Bb = fcwb + (size_t)(bn * 128) * 1024;
      unsigned short* AlsW = &Als[w * 1024];
      unsigned short* BlsW = &Bls[w * 1024];
      f32x4 acc[4][4] = {};
      for (int kk = 0; kk < 1024; kk += 32) {
        __syncthreads();
        gload_lds16(Ab + (size_t)row0 * 1024 + kk + ks0, AlsW);
        gload_lds16(Ab + (size_t)row1 * 1024 + kk + ks1, AlsW + 512);
        gload_lds16(Bb + (size_t)row0 * 1024 + kk + ks0, BlsW);
        gload_lds16(Bb + (size_t)row1 * 1024 + kk + ks1, BlsW + 512);
        __syncthreads();
        short8 af[4], bfr[4];
#pragma unroll
        for (int r = 0; r < 4; r++)
          af[r] = *(const short8*)&Als[(wr * 64 + r * 16 + lr) * 32 + co];
#pragma unroll
        for (int c4 = 0; c4 < 4; c4++)
          bfr[c4] = *(const short8*)&Bls[(wc * 64 + c4 * 16 + lr) * 32 + co];
#pragma unroll
        for (int r = 0; r < 4; r++)
#pragma unroll
          for (int c4 = 0; c4 < 4; c4++)
            acc[r][c4] = __builtin_amdgcn_mfma_f32_16x16x32_bf16(af[r], bfr[c4], acc[r][c4], 0, 0, 0);
      }
      int rbase = bm * 128 + wr * 64 + hi * 4;
      int cbase = bn * 128 + wc * 64 + lr;
#pragma unroll
      for (int r = 0; r < 4; r++) {
#pragma unroll
        for (int c4 = 0; c4 < 4; c4++) {
          int cc = cbase + c4 * 16;
          float bv = fcb[cc];
#pragma unroll
          for (int jx = 0; jx < 4; jx++) {
            int rr = rbase + r * 16 + jx;
            size_t orow = (size_t)((rr & 63) * 64 + (rr >> 6));
            __builtin_nontemporal_store(acc[r][c4][jx] + bv, &dout[orow * V_ + cc]);
          }
        }
      }
    };
    int last_bm = -1;
    for (int k = 0; k < 25; ++k) {
      int ln = p + 320 * k;
      int bm = ln / 250, bn = ln - bm * 250;
      if (bn >= 234) continue;
      if (bm != last_bm) {
        if (tid < 2) spin_ge_slow(&agg1[(2 * bm + tid) * 16], 64);
        __syncthreads();
        last_bm = bm;
      }
      tile(bm, bn);
    }
    // tail v-panels overlap the G0 storage: wait until l1 fully done
    // (agg1[63]==64 implies cnt0[63] full => l0 finished all G0 reads).
    if (tid == 0) spin_ge_slow(&agg1[63 * 16], 64);
    __syncthreads();
    for (int k = 0; k < 25; ++k) {
      int ln = p + 320 * k;
      int bm = ln / 250, bn = ln - bm * 250;
      if (bn < 234) continue;
      tile(bm, bn);
    }
  }
}

extern "C" void kernel_launch(void* const* d_in, const int* in_sizes, int n_in,
                              void* d_out, int out_size, void* d_ws, size_t ws_size,
                              hipStream_t stream) {
  const float* hidden = (const float*)d_in[0];
  const float* cell   = (const float*)d_in[1];
  const int*   Y      = (const int*)d_in[2];
  const float* emb    = (const float*)d_in[3];
  const float* wih0   = (const float*)d_in[4];
  const float* whh0   = (const float*)d_in[5];
  const float* bih0   = (const float*)d_in[6];
  const float* bhh0   = (const float*)d_in[7];
  const float* wih1   = (const float*)d_in[8];
  const float* whh1   = (const float*)d_in[9];
  const float* bih1   = (const float*)d_in[10];
  const float* bhh1   = (const float*)d_in[11];
  const float* fcw    = (const float*)d_in[12];
  const float* fcb    = (const float*)d_in[13];

  char* ws = (char*)d_ws;
  size_t off = 0;
  auto alloc = [&](size_t bytes) {
    void* p = ws + off;
    off += (bytes + 255) & ~(size_t)255;
    return p;
  };
  unsigned short* wih0b = (unsigned short*)alloc((size_t)2 * G4 * E_ * 2);
  unsigned short* whh0b = (unsigned short*)alloc((size_t)2 * G4 * H_ * 2);
  unsigned short* wih1b = (unsigned short*)alloc((size_t)2 * G4 * 1024 * 2);
  unsigned short* whh1b = (unsigned short*)alloc((size_t)2 * G4 * H_ * 2);
  unsigned short* fcwb  = (unsigned short*)alloc((size_t)V_ * 1024 * 2);
  unsigned short* Xb    = (unsigned short*)alloc((size_t)SB * E_ * 2);
  unsigned short* H0    = (unsigned short*)alloc((size_t)SB * 1024 * 2);
  unsigned short* O1    = (unsigned short*)alloc((size_t)SB * 1024 * 2);
  unsigned short* h0i   = (unsigned short*)alloc((size_t)2 * B_ * H_ * 2);
  unsigned short* h1i   = (unsigned short*)alloc((size_t)2 * B_ * H_ * 2);
  float* b0s = (float*)alloc((size_t)2 * G4 * 4);
  float* b1s = (float*)alloc((size_t)2 * G4 * 4);
  unsigned* cnt0 = (unsigned*)alloc(CNT_BYTES);
  unsigned* cnt1 = (unsigned*)alloc(CNT_BYTES);
  unsigned* agg1 = (unsigned*)alloc(AGG_BYTES);
  (void)ws_size;

  // --- prep ---
  k_f2bf<<<2048, 256, 0, stream>>>(wih0, wih0b, 2 * G4 * E_);
  k_f2bf<<<2048, 256, 0, stream>>>(whh0, whh0b, 2 * G4 * H_);
  k_f2bf<<<2048, 256, 0, stream>>>(wih1, wih1b, 2 * G4 * 1024);
  k_f2bf<<<2048, 256, 0, stream>>>(whh1, whh1b, 2 * G4 * H_);
  k_f2bf<<<4096, 256, 0, stream>>>(fcw, fcwb, V_ * 1024);
  k_addbias<<<16, 256, 0, stream>>>(bih0, bhh0, b0s, 2 * G4);
  k_addbias<<<16, 256, 0, stream>>>(bih1, bhh1, b1s, 2 * G4);
  k_gather<<<SB, 256, 0, stream>>>(Y, emb, Xb);
  k_init_h<<<512, 256, 0, stream>>>(hidden, h0i, h1i);
  (void)hipMemsetAsync(cnt0, 0, CNT_BYTES, stream);
  (void)hipMemsetAsync(cnt1, 0, CNT_BYTES, stream);
  (void)hipMemsetAsync(agg1, 0, AGG_BYTES, stream);

  // --- layer-0 input gates -> bf16 G0 in d_out row tails ---
  k_gemm_g0<<<1024, 256, 0, stream>>>(Xb, wih0b, b0s, (unsigned short*)d_out,
                                      E_, SB / 128, 1024);

  // --- mega: recurrence + co-resident overlapped projection ---
  k_mega<<<448, 256, 0, stream>>>(h0i, h1i, cell, whh0b, wih1b, whh1b, b1s,
                                  (float*)d_out, fcwb, fcb, H0, O1,
                                  cnt0, cnt1, agg1);
}

// Round 12
// 1666.695 us; speedup vs baseline: 1.5160x; 1.0911x over previous
//
#include <hip/hip_runtime.h>
#include <hip/hip_bf16.h>
#include <stdint.h>

#define S_ 64
#define B_ 64
#define E_ 512
#define H_ 512
#define V_ 32000
#define G4 2048   // 4*H
#define SB 4096   // S*B

// d_out row = 32000 fp32 = 64000 ushort; G0 (bf16) lives in the tail 4096
// ushorts of each row: G0(sb, d, c) at ushort index sb*64000 + 59904 + d*2048 + c.
#define OROW_US 64000
#define GTAIL_US 59904   // 29952 fp32 * 2

typedef __attribute__((ext_vector_type(8))) short short8;
typedef __attribute__((ext_vector_type(4))) float f32x4;
typedef __attribute__((ext_vector_type(4))) int i32x4;

static __device__ __forceinline__ unsigned short f2bf(float f) {
  unsigned u = __float_as_uint(f);
  u += 0x7fff + ((u >> 16) & 1);   // RNE
  return (unsigned short)(u >> 16);
}
static __device__ __forceinline__ float bf2f(unsigned short u) {
  return __uint_as_float((unsigned)u << 16);
}
static __device__ __forceinline__ float sigm(float x) {
  return 1.f / (1.f + expf(-x));
}

__device__ __forceinline__ void gload_lds16(const void* g, void* l) {
  __builtin_amdgcn_global_load_lds(
      (const __attribute__((address_space(1))) void*)g,
      (__attribute__((address_space(3))) void*)l, 16, 0, 0);
}

// coherent (device-visible) 16-byte store: write-through past the XCD L2
__device__ __forceinline__ void st128_sys(void* p, i32x4 v) {
  asm volatile("global_store_dwordx4 %0, %1, off sc0 sc1"
               :: "v"((unsigned long long)p), "v"(v) : "memory");
}
__device__ __forceinline__ void wait_vm0() {
  asm volatile("s_waitcnt vmcnt(0)" ::: "memory");
}

__device__ __forceinline__ void spin_ge(unsigned* c, unsigned tgt) {
  while (__hip_atomic_load(c, __ATOMIC_RELAXED, __HIP_MEMORY_SCOPE_AGENT) < tgt)
    __builtin_amdgcn_s_sleep(8);
}
__device__ __forceinline__ void spin_ge_slow(unsigned* c, unsigned tgt) {
  while (__hip_atomic_load(c, __ATOMIC_RELAXED, __HIP_MEMORY_SCOPE_AGENT) < tgt)
    __builtin_amdgcn_s_sleep(64);
}
__device__ __forceinline__ void arrive(unsigned* c) {
  __hip_atomic_fetch_add(c, 1u, __ATOMIC_RELAXED, __HIP_MEMORY_SCOPE_AGENT);
}

// fine-grain counter slot: per (step, dir, part), 256B apart (R8-proven)
#define CIDX(t, d, p) ((((t) * 8) + ((d) * 4) + (p)) * 64)
// sync layout (uints): cnt0 @0 (32768), cnt1 @32768 (32768), agg1 @65536 (64*16)
#define SYNC_UINTS 66560

__global__ void k_f2bf(const float* __restrict__ in, unsigned short* __restrict__ out, int n) {
  int i = blockIdx.x * blockDim.x + threadIdx.x;
  int stride = gridDim.x * blockDim.x;
  for (; i < n; i += stride) out[i] = f2bf(in[i]);
}

__global__ void k_addbias(const float* __restrict__ a, const float* __restrict__ b,
                          float* __restrict__ out, int n) {
  int i = blockIdx.x * blockDim.x + threadIdx.x;
  if (i < n) out[i] = a[i] + b[i];
}

__global__ void k_gather(const int* __restrict__ Y, const float* __restrict__ emb,
                         unsigned short* __restrict__ X) {
  int sb = blockIdx.x;
  int t = sb >> 6, b = sb & 63;
  int idx = (t == 0) ? Y[b * S_ + 1] : Y[b * S_ + t - 1];
  const float* src = emb + (size_t)idx * E_;
  unsigned short* dst = X + (size_t)sb * E_;
  for (int e = threadIdx.x; e < E_; e += blockDim.x) dst[e] = f2bf(src[e]);
}

__global__ void k_init_h(const float* __restrict__ hid,
                         unsigned short* __restrict__ h0i, unsigned short* __restrict__ h1i) {
  int i = blockIdx.x * blockDim.x + threadIdx.x;
  if (i >= 4 * B_ * H_) return;
  unsigned short v = f2bf(hid[i]);
  if (i < 2 * B_ * H_) h0i[i] = v;
  else h1i[i - 2 * B_ * H_] = v;
}

// ---------------- G0 GEMM: bf16 into d_out row tails (R10-proven) ----------------
__global__ __launch_bounds__(256) void k_gemm_g0(
    const unsigned short* __restrict__ A, const unsigned short* __restrict__ B,
    const float* __restrict__ bias, unsigned short* __restrict__ C,
    int K, int nTM, int nwg) {
  __shared__ unsigned short Als[128 * 32];
  __shared__ unsigned short Bls[128 * 32];
  int tid = threadIdx.x;
  int o = blockIdx.x;
  int wg = (o & 7) * (nwg >> 3) + (o >> 3);
  int bm = wg % nTM, bn = wg / nTM;
  int w = tid >> 6, l = tid & 63;
  int wr = w >> 1, wc = w & 1;
  int lr = l & 15, hi = l >> 4;
  int c0 = w * 128 + l;
  int row0 = c0 >> 2, ks0 = (((c0 & 3) ^ (row0 & 3)) * 8);
  int c1 = c0 + 64;
  int row1 = c1 >> 2, ks1 = (((c1 & 3) ^ (row1 & 3)) * 8);
  const unsigned short* Ab = A + (size_t)(bm * 128) * K;
  const unsigned short* Bb = B + (size_t)(bn * 128) * K;
  unsigned short* AlsW = &Als[w * 1024];
  unsigned short* BlsW = &Bls[w * 1024];
  int co = ((hi ^ (lr & 3)) * 8);
  f32x4 acc[4][4] = {};
  for (int kk = 0; kk < K; kk += 32) {
    __syncthreads();
    gload_lds16(Ab + (size_t)row0 * K + kk + ks0, AlsW);
    gload_lds16(Ab + (size_t)row1 * K + kk + ks1, AlsW + 512);
    gload_lds16(Bb + (size_t)row0 * K + kk + ks0, BlsW);
    gload_lds16(Bb + (size_t)row1 * K + kk + ks1, BlsW + 512);
    __syncthreads();
    short8 af[4], bfr[4];
#pragma unroll
    for (int r = 0; r < 4; r++)
      af[r] = *(const short8*)&Als[(wr * 64 + r * 16 + lr) * 32 + co];
#pragma unroll
    for (int c4 = 0; c4 < 4; c4++)
      bfr[c4] = *(const short8*)&Bls[(wc * 64 + c4 * 16 + lr) * 32 + co];
#pragma unroll
    for (int r = 0; r < 4; r++)
#pragma unroll
      for (int c4 = 0; c4 < 4; c4++)
        acc[r][c4] = __builtin_amdgcn_mfma_f32_16x16x32_bf16(af[r], bfr[c4], acc[r][c4], 0, 0, 0);
  }
  int rbase = bm * 128 + wr * 64 + hi * 4;
  int cbase = bn * 128 + wc * 64 + lr;
#pragma unroll
  for (int r = 0; r < 4; r++) {
#pragma unroll
    for (int c4 = 0; c4 < 4; c4++) {
      int cc = cbase + c4 * 16;
      float bv = bias[cc];
#pragma unroll
      for (int j = 0; j < 4; j++) {
        int rr = rbase + r * 16 + j;
        C[(size_t)rr * OROW_US + GTAIL_US + cc] = f2bf(acc[r][c4][j] + bv);
      }
    }
  }
}

// ---------------- MEGA: rec (256 blocks, 33KB) + proj (768 blocks, static) ----------------
// [0,128): layer 0  — d=blk>>6, jt8=blk&63, 8 j-cols, 2-gate-packed whh0 in LDS,
//          G0 (bf16) from d_out tails.
// [128,256): layer 1 — same shape; whh1 in LDS, wih1 read from global in the
//          pipelined x1 phase (off the recurrent chain).
// [256,1024): projection — static tiles ln = p + 768k over bm-major (bn<234),
//          gated per bm on agg1[2bm], agg1[2bm+1] >= 128.
// Tail panels (bn in [234,250), the G0 region): 1 tile each on blocks [0,512),
//          gated on agg1[63] >= 128 (l1 done => l0 done reading G0).
// All 1024 blocks resident (LDS 34.5KB x4 = 138KB, 88 VGPR <= 128, 16 waves/CU).
#define LDWr 520    // 32 rows x (512+8)

__global__ __launch_bounds__(256, 4) void k_mega(
    const unsigned short* __restrict__ h0i,   // (2,B,H) bf16
    const unsigned short* __restrict__ h1i,   // (2,B,H) bf16
    const float* __restrict__ cell,           // (4,B,H) fp32
    const unsigned short* __restrict__ whh0,  // (2,2048,512) bf16
    const unsigned short* __restrict__ wih1,  // (2,2048,1024) bf16
    const unsigned short* __restrict__ whh1,  // (2,2048,512) bf16
    const float* __restrict__ b1s,            // (2,2048) fp32
    float* __restrict__ dout,                 // output + G0 tails
    const unsigned short* __restrict__ fcwb,  // (V,1024) bf16
    const float* __restrict__ fcb,            // (V,) fp32
    unsigned short* __restrict__ H0,          // (SB,1024) bf16
    unsigned short* __restrict__ O1,          // (SB,1024) bf16
    unsigned* __restrict__ sync) {
  __shared__ unsigned short SM[32 * LDWr];              // 33,280 B
  __shared__ __align__(16) unsigned short HS[64 * 8];   // publish staging
  unsigned* cnt0 = sync;
  unsigned* cnt1 = sync + 32768;
  unsigned* agg1 = sync + 65536;
  int tid = threadIdx.x;
  int w = tid >> 6, l = tid & 63;
  int lr = l & 15, hi = l >> 4;
  const unsigned short* G0u = (const unsigned short*)dout;

  // ---- shared projection-tile machinery (proj blocks + tail phase) ----
  int wr = w >> 1, wc = w & 1;
  int c0 = w * 128 + l;
  int row0 = c0 >> 2, ks0 = (((c0 & 3) ^ (row0 & 3)) * 8);
  int c1 = c0 + 64;
  int row1 = c1 >> 2, ks1 = (((c1 & 3) ^ (row1 & 3)) * 8);
  int co = ((hi ^ (lr & 3)) * 8);
  unsigned short* Als = SM;
  unsigned short* Bls = SM + 4096;
  auto tile = [&](int bm, int bn) {
    const unsigned short* Ab = O1 + (size_t)(bm * 128) * 1024;
    const unsigned short* Bb = fcwb + (size_t)(bn * 128) * 1024;
    unsigned short* AlsW = &Als[w * 1024];
    unsigned short* BlsW = &Bls[w * 1024];
    f32x4 acc[4][4] = {};
    for (int kk = 0; kk < 1024; kk += 32) {
      __syncthreads();
      gload_lds16(Ab + (size_t)row0 * 1024 + kk + ks0, AlsW);
      gload_lds16(Ab + (size_t)row1 * 1024 + kk + ks1, AlsW + 512);
      gload_lds16(Bb + (size_t)row0 * 1024 + kk + ks0, BlsW);
      gload_lds16(Bb + (size_t)row1 * 1024 + kk + ks1, BlsW + 512);
      __syncthreads();
      short8 af[4], bfr[4];
#pragma unroll
      for (int r = 0; r < 4; r++)
        af[r] = *(const short8*)&Als[(wr * 64 + r * 16 + lr) * 32 + co];
#pragma unroll
      for (int c4 = 0; c4 < 4; c4++)
        bfr[c4] = *(const short8*)&Bls[(wc * 64 + c4 * 16 + lr) * 32 + co];
#pragma unroll
      for (int r = 0; r < 4; r++)
#pragma unroll
        for (int c4 = 0; c4 < 4; c4++)
          acc[r][c4] = __builtin_amdgcn_mfma_f32_16x16x32_bf16(af[r], bfr[c4], acc[r][c4], 0, 0, 0);
    }
    int rbase = bm * 128 + wr * 64 + hi * 4;
    int cbase = bn * 128 + wc * 64 + lr;
#pragma unroll
    for (int r = 0; r < 4; r++) {
#pragma unroll
      for (int c4 = 0; c4 < 4; c4++) {
        int cc = cbase + c4 * 16;
        float bv = fcb[cc];
#pragma unroll
        for (int jx = 0; jx < 4; jx++) {
          int rr = rbase + r * 16 + jx;
          size_t orow = (size_t)((rr & 63) * 64 + (rr >> 6));
          __builtin_nontemporal_store(acc[r][c4][jx] + bv, &dout[orow * V_ + cc]);
        }
      }
    }
  };

  if (blockIdx.x < 256) {
    // ================= RECURRENCE (8 j-cols, 2-gate-packed, R8-l1 shape) =========
    bool isL0 = blockIdx.x < 128;
    int idx = isL0 ? blockIdx.x : blockIdx.x - 128;
    int d = idx >> 6, jt8 = idx & 63;
    int j0 = jt8 * 8;
    const unsigned short* Wd = (isL0 ? whh0 : whh1) + (size_t)d * (G4 * H_);
    for (int c = tid; c < 32 * 64; c += 256) {
      int r = c >> 6, ck = c & 63;
      int g = r >> 3, jc = r & 7;
      *(int4*)&SM[r * LDWr + ck * 8] =
          *(const int4*)&Wd[(size_t)(g * H_ + j0 + jc) * H_ + ck * 8];
    }
    int j = j0 + (lr & 7);
    int b0 = w * 16 + hi * 4;
    f32x4 creg = {};
    if (lr < 8) {
      const float* cd = cell + (size_t)((isL0 ? 0 : 2) + d) * (B_ * H_);
#pragma unroll
      for (int jj = 0; jj < 4; jj++) creg[jj] = cd[(size_t)(b0 + jj) * H_ + j];
    }
    __syncthreads();

    if (isL0) {
      float gv[4][4];
      auto preloadG = [&](int t) {
#pragma unroll
        for (int jj = 0; jj < 4; jj++) {
          const unsigned short* Gb =
              G0u + (size_t)(t * B_ + b0 + jj) * OROW_US + GTAIL_US + d * 2048 + j;
#pragma unroll
          for (int g = 0; g < 4; g++) gv[g][jj] = bf2f(Gb[g * 512]);
        }
      };
      preloadG(0);
      for (int t = 0; t < S_; ++t) {
        if (t >= 1) {
          if (tid < 4) spin_ge(&cnt0[CIDX(t - 1, d, tid)], 16);
          __syncthreads();
        }
        const unsigned short* hp = (t == 0) ? h0i + (size_t)d * (B_ * H_)
                                            : H0 + (size_t)(t - 1) * B_ * 1024 + d * 512;
        size_t hstr = (t == 0) ? (size_t)H_ : 1024;
        const unsigned short* arow = hp + (size_t)(w * 16 + lr) * hstr + hi * 8;
        f32x4 acc0 = {}, acc1 = {};
#pragma unroll
        for (int ki = 0; ki < 16; ki++) {
          short8 a = *(const short8*)&arow[ki * 32];
          short8 bA = *(const short8*)&SM[lr * LDWr + ki * 32 + hi * 8];
          short8 bB = *(const short8*)&SM[(16 + lr) * LDWr + ki * 32 + hi * 8];
          acc0 = __builtin_amdgcn_mfma_f32_16x16x32_bf16(a, bA, acc0, 0, 0, 0);
          acc1 = __builtin_amdgcn_mfma_f32_16x16x32_bf16(a, bB, acc1, 0, 0, 0);
        }
        float pf[4], po[4];
#pragma unroll
        for (int jj = 0; jj < 4; jj++) {
          pf[jj] = __shfl_xor(acc0[jj], 8);
          po[jj] = __shfl_xor(acc1[jj], 8);
        }
        if (lr < 8) {
#pragma unroll
          for (int jj = 0; jj < 4; jj++) {
            float gi = acc0[jj] + gv[0][jj];
            float gf = pf[jj] + gv[1][jj];
            float gg = acc1[jj] + gv[2][jj];
            float go = po[jj] + gv[3][jj];
            float c = sigm(gf) * creg[jj] + sigm(gi) * tanhf(gg);
            creg[jj] = c;
            HS[(b0 + jj) * 8 + lr] = f2bf(sigm(go) * tanhf(c));
          }
        }
        __syncthreads();
        unsigned short* Ho = H0 + (size_t)t * B_ * 1024 + d * 512 + j0;
        if (tid < 64) st128_sys(&Ho[(size_t)tid * 1024], *(const i32x4*)&HS[tid * 8]);
        wait_vm0();
        __syncthreads();
        if (tid == 0) arrive(&cnt0[CIDX(t, d, jt8 & 3)]);
        if (t + 1 < S_) preloadG(t + 1);
      }
    } else {
      // layer 1: whh in LDS; wih1 gates computed from GLOBAL in pipelined x1 phase
      const float* b1d = b1s + d * G4;
      float bi_ = b1d[j], bf_ = b1d[512 + j], bg_ = b1d[1024 + j], bo_ = b1d[1536 + j];
      const unsigned short* Wg0 = wih1 + (size_t)d * (G4 * 1024) +
          (size_t)((lr >> 3) * H_ + j0 + (lr & 7)) * 1024 + hi * 8;
      const unsigned short* Wg1 = wih1 + (size_t)d * (G4 * 1024) +
          (size_t)((2 + (lr >> 3)) * H_ + j0 + (lr & 7)) * 1024 + hi * 8;
      f32x4 acc0, acc1;
      auto x1phase = [&](int t) {
        if (tid < 8) spin_ge(&cnt0[CIDX(t, 0, 0) + tid * 64], 16);
        __syncthreads();
        acc0 = (f32x4){}; acc1 = (f32x4){};
        const unsigned short* x1row = H0 + ((size_t)t * B_ + w * 16 + lr) * 1024 + hi * 8;
#pragma unroll 8
        for (int ki = 0; ki < 32; ki++) {
          short8 a = *(const short8*)&x1row[ki * 32];
          short8 bA = *(const short8*)&Wg0[ki * 32];
          short8 bB = *(const short8*)&Wg1[ki * 32];
          acc0 = __builtin_amdgcn_mfma_f32_16x16x32_bf16(a, bA, acc0, 0, 0, 0);
          acc1 = __builtin_amdgcn_mfma_f32_16x16x32_bf16(a, bB, acc1, 0, 0, 0);
        }
      };
      x1phase(0);
      for (int t = 0; t < S_; ++t) {
        if (t >= 1) {
          if (tid < 4) spin_ge(&cnt1[CIDX(t - 1, d, tid)], 16);
          __syncthreads();
        }
        const unsigned short* hprev = (t == 0)
            ? h1i + (size_t)d * (B_ * H_) + (size_t)(w * 16 + lr) * H_ + hi * 8
            : O1 + ((size_t)(t - 1) * B_ + w * 16 + lr) * 1024 + d * 512 + hi * 8;
#pragma unroll
        for (int ki = 0; ki < 16; ki++) {
          short8 a = *(const short8*)&hprev[ki * 32];
          short8 bA = *(const short8*)&SM[lr * LDWr + ki * 32 + hi * 8];
          short8 bB = *(const short8*)&SM[(16 + lr) * LDWr + ki * 32 + hi * 8];
          acc0 = __builtin_amdgcn_mfma_f32_16x16x32_bf16(a, bA, acc0, 0, 0, 0);
          acc1 = __builtin_amdgcn_mfma_f32_16x16x32_bf16(a, bB, acc1, 0, 0, 0);
        }
        float pf[4], po[4];
#pragma unroll
        for (int jj = 0; jj < 4; jj++) {
          pf[jj] = __shfl_xor(acc0[jj], 8);
          po[jj] = __shfl_xor(acc1[jj], 8);
        }
        if (lr < 8) {
#pragma unroll
          for (int jj = 0; jj < 4; jj++) {
            float gi = acc0[jj] + bi_;
            float gf = pf[jj] + bf_;
            float gg = acc1[jj] + bg_;
            float go = po[jj] + bo_;
            float c = sigm(gf) * creg[jj] + sigm(gi) * tanhf(gg);
            creg[jj] = c;
            HS[(b0 + jj) * 8 + lr] = f2bf(sigm(go) * tanhf(c));
          }
        }
        __syncthreads();
        unsigned short* Oo = O1 + (size_t)t * B_ * 1024 + d * 512 + j0;
        if (tid < 64) st128_sys(&Oo[(size_t)tid * 1024], *(const i32x4*)&HS[tid * 8]);
        wait_vm0();
        __syncthreads();
        if (tid == 0) arrive(&cnt1[CIDX(t, d, jt8 & 3)]);
        if (tid == 64) arrive(&agg1[t * 16]);
        if (t + 1 < S_) x1phase(t + 1);
      }
    }
  } else {
    // ================= PROJECTION (768 blocks, static, frontier-gated) ==========
    int p = blockIdx.x - 256;
    for (int ln = p; ln < 7488; ln += 768) {
      int bm = ln / 234, bn = ln - bm * 234;
      if (tid < 2) spin_ge_slow(&agg1[(2 * bm + tid) * 16], 128);
      __syncthreads();
      tile(bm, bn);
    }
  }

  // ---- tail panels (G0-tail region, bn in [234,250)): blocks [0,512), 1 each ----
  if (blockIdx.x < 512) {
    if (tid == 0) spin_ge_slow(&agg1[63 * 16], 128);
    __syncthreads();
    int ln = blockIdx.x;
    tile(ln >> 4, 234 + (ln & 15));
  }
}

extern "C" void kernel_launch(void* const* d_in, const int* in_sizes, int n_in,
                              void* d_out, int out_size, void* d_ws, size_t ws_size,
                              hipStream_t stream) {
  const float* hidden = (const float*)d_in[0];
  const float* cell   = (const float*)d_in[1];
  const int*   Y      = (const int*)d_in[2];
  const float* emb    = (const float*)d_in[3];
  const float* wih0   = (const float*)d_in[4];
  const float* whh0   = (const float*)d_in[5];
  const float* bih0   = (const float*)d_in[6];
  const float* bhh0   = (const float*)d_in[7];
  const float* wih1   = (const float*)d_in[8];
  const float* whh1   = (const float*)d_in[9];
  const float* bih1   = (const float*)d_in[10];
  const float* bhh1   = (const float*)d_in[11];
  const float* fcw    = (const float*)d_in[12];
  const float* fcb    = (const float*)d_in[13];

  char* ws = (char*)d_ws;
  size_t off = 0;
  auto alloc = [&](size_t bytes) {
    void* p = ws + off;
    off += (bytes + 255) & ~(size_t)255;
    return p;
  };
  unsigned short* wih0b = (unsigned short*)alloc((size_t)2 * G4 * E_ * 2);
  unsigned short* whh0b = (unsigned short*)alloc((size_t)2 * G4 * H_ * 2);
  unsigned short* wih1b = (unsigned short*)alloc((size_t)2 * G4 * 1024 * 2);
  unsigned short* whh1b = (unsigned short*)alloc((size_t)2 * G4 * H_ * 2);
  unsigned short* fcwb  = (unsigned short*)alloc((size_t)V_ * 1024 * 2);
  unsigned short* Xb    = (unsigned short*)alloc((size_t)SB * E_ * 2);
  unsigned short* H0    = (unsigned short*)alloc((size_t)SB * 1024 * 2);
  unsigned short* O1    = (unsigned short*)alloc((size_t)SB * 1024 * 2);
  unsigned short* h0i   = (unsigned short*)alloc((size_t)2 * B_ * H_ * 2);
  unsigned short* h1i   = (unsigned short*)alloc((size_t)2 * B_ * H_ * 2);
  float* b0s = (float*)alloc((size_t)2 * G4 * 4);
  float* b1s = (float*)alloc((size_t)2 * G4 * 4);
  unsigned* syncbuf = (unsigned*)alloc((size_t)SYNC_UINTS * 4);
  (void)ws_size;

  // --- prep (R8-proven kernels) ---
  k_f2bf<<<2048, 256, 0, stream>>>(wih0, wih0b, 2 * G4 * E_);
  k_f2bf<<<2048, 256, 0, stream>>>(whh0, whh0b, 2 * G4 * H_);
  k_f2bf<<<2048, 256, 0, stream>>>(wih1, wih1b, 2 * G4 * 1024);
  k_f2bf<<<2048, 256, 0, stream>>>(whh1, whh1b, 2 * G4 * H_);
  k_f2bf<<<4096, 256, 0, stream>>>(fcw, fcwb, V_ * 1024);
  k_addbias<<<16, 256, 0, stream>>>(bih0, bhh0, b0s, 2 * G4);
  k_addbias<<<16, 256, 0, stream>>>(bih1, bhh1, b1s, 2 * G4);
  k_gather<<<SB, 256, 0, stream>>>(Y, emb, Xb);
  k_init_h<<<512, 256, 0, stream>>>(hidden, h0i, h1i);
  (void)hipMemsetAsync(syncbuf, 0, (size_t)SYNC_UINTS * 4, stream);

  // --- layer-0 input gates -> bf16 G0 in d_out row tails ---
  k_gemm_g0<<<1024, 256, 0, stream>>>(Xb, wih0b, b0s, (unsigned short*)d_out,
                                      E_, SB / 128, 1024);

  // --- mega: recurrence + co-resident overlapped projection ---
  k_mega<<<1024, 256, 0, stream>>>(h0i, h1i, cell, whh0b, wih1b, whh1b, b1s,
                                   (float*)d_out, fcwb, fcb, H0, O1, syncbuf);
}

// Round 13
// 1663.302 us; speedup vs baseline: 1.5191x; 1.0020x over previous
//
#include <hip/hip_runtime.h>
#include <hip/hip_bf16.h>
#include <stdint.h>

#define S_ 64
#define B_ 64
#define E_ 512
#define H_ 512
#define V_ 32000
#define G4 2048   // 4*H
#define SB 4096   // S*B

// d_out row = 32000 fp32 = 64000 ushort; G0 (bf16) lives in the tail 4096
// ushorts of each row: G0(sb, d, c) at ushort index sb*64000 + 59904 + d*2048 + c.
#define OROW_US 64000
#define GTAIL_US 59904   // 29952 fp32 * 2

typedef __attribute__((ext_vector_type(8))) short short8;
typedef __attribute__((ext_vector_type(4))) float f32x4;
typedef __attribute__((ext_vector_type(4))) int i32x4;

static __device__ __forceinline__ unsigned short f2bf(float f) {
  unsigned u = __float_as_uint(f);
  u += 0x7fff + ((u >> 16) & 1);   // RNE
  return (unsigned short)(u >> 16);
}
static __device__ __forceinline__ float bf2f(unsigned short u) {
  return __uint_as_float((unsigned)u << 16);
}
static __device__ __forceinline__ float sigm(float x) {
  return 1.f / (1.f + expf(-x));
}

__device__ __forceinline__ void gload_lds16(const void* g, void* l) {
  __builtin_amdgcn_global_load_lds(
      (const __attribute__((address_space(1))) void*)g,
      (__attribute__((address_space(3))) void*)l, 16, 0, 0);
}

// coherent (device-visible) 16-byte store: write-through past the XCD L2
__device__ __forceinline__ void st128_sys(void* p, i32x4 v) {
  asm volatile("global_store_dwordx4 %0, %1, off sc0 sc1"
               :: "v"((unsigned long long)p), "v"(v) : "memory");
}
__device__ __forceinline__ void wait_vm0() {
  asm volatile("s_waitcnt vmcnt(0)" ::: "memory");
}

// fast spin for the latency-critical recurrence chain
__device__ __forceinline__ void spin_ge(unsigned* c, unsigned tgt) {
  while (__hip_atomic_load(c, __ATOMIC_RELAXED, __HIP_MEMORY_SCOPE_AGENT) < tgt)
    __builtin_amdgcn_s_sleep(1);
}
// slow spin for projection frontier gates
__device__ __forceinline__ void spin_ge_slow(unsigned* c, unsigned tgt) {
  while (__hip_atomic_load(c, __ATOMIC_RELAXED, __HIP_MEMORY_SCOPE_AGENT) < tgt)
    __builtin_amdgcn_s_sleep(64);
}
__device__ __forceinline__ void arrive(unsigned* c) {
  __hip_atomic_fetch_add(c, 1u, __ATOMIC_RELAXED, __HIP_MEMORY_SCOPE_AGENT);
}

// fine-grain counter slot: per (step, dir, part), 256B apart (R8-proven)
#define CIDX(t, d, p) ((((t) * 8) + ((d) * 4) + (p)) * 64)
// sync layout (uints): cnt0 @0 (32768), cnt1 @32768 (32768), agg1 @65536 (64*16)
#define SYNC_UINTS 66560

__global__ void k_f2bf(const float* __restrict__ in, unsigned short* __restrict__ out, int n) {
  int i = blockIdx.x * blockDim.x + threadIdx.x;
  int stride = gridDim.x * blockDim.x;
  for (; i < n; i += stride) out[i] = f2bf(in[i]);
}

__global__ void k_addbias(const float* __restrict__ a, const float* __restrict__ b,
                          float* __restrict__ out, int n) {
  int i = blockIdx.x * blockDim.x + threadIdx.x;
  if (i < n) out[i] = a[i] + b[i];
}

__global__ void k_gather(const int* __restrict__ Y, const float* __restrict__ emb,
                         unsigned short* __restrict__ X) {
  int sb = blockIdx.x;
  int t = sb >> 6, b = sb & 63;
  int idx = (t == 0) ? Y[b * S_ + 1] : Y[b * S_ + t - 1];
  const float* src = emb + (size_t)idx * E_;
  unsigned short* dst = X + (size_t)sb * E_;
  for (int e = threadIdx.x; e < E_; e += blockDim.x) dst[e] = f2bf(src[e]);
}

__global__ void k_init_h(const float* __restrict__ hid,
                         unsigned short* __restrict__ h0i, unsigned short* __restrict__ h1i) {
  int i = blockIdx.x * blockDim.x + threadIdx.x;
  if (i >= 4 * B_ * H_) return;
  unsigned short v = f2bf(hid[i]);
  if (i < 2 * B_ * H_) h0i[i] = v;
  else h1i[i - 2 * B_ * H_] = v;
}

// ---------------- G0 GEMM: bf16 into d_out row tails (R10-proven) ----------------
__global__ __launch_bounds__(256) void k_gemm_g0(
    const unsigned short* __restrict__ A, const unsigned short* __restrict__ B,
    const float* __restrict__ bias, unsigned short* __restrict__ C,
    int K, int nTM, int nwg) {
  __shared__ unsigned short Als[128 * 32];
  __shared__ unsigned short Bls[128 * 32];
  int tid = threadIdx.x;
  int o = blockIdx.x;
  int wg = (o & 7) * (nwg >> 3) + (o >> 3);
  int bm = wg % nTM, bn = wg / nTM;
  int w = tid >> 6, l = tid & 63;
  int wr = w >> 1, wc = w & 1;
  int lr = l & 15, hi = l >> 4;
  int c0 = w * 128 + l;
  int row0 = c0 >> 2, ks0 = (((c0 & 3) ^ (row0 & 3)) * 8);
  int c1 = c0 + 64;
  int row1 = c1 >> 2, ks1 = (((c1 & 3) ^ (row1 & 3)) * 8);
  const unsigned short* Ab = A + (size_t)(bm * 128) * K;
  const unsigned short* Bb = B + (size_t)(bn * 128) * K;
  unsigned short* AlsW = &Als[w * 1024];
  unsigned short* BlsW = &Bls[w * 1024];
  int co = ((hi ^ (lr & 3)) * 8);
  f32x4 acc[4][4] = {};
  for (int kk = 0; kk < K; kk += 32) {
    __syncthreads();
    gload_lds16(Ab + (size_t)row0 * K + kk + ks0, AlsW);
    gload_lds16(Ab + (size_t)row1 * K + kk + ks1, AlsW + 512);
    gload_lds16(Bb + (size_t)row0 * K + kk + ks0, BlsW);
    gload_lds16(Bb + (size_t)row1 * K + kk + ks1, BlsW + 512);
    __syncthreads();
    short8 af[4], bfr[4];
#pragma unroll
    for (int r = 0; r < 4; r++)
      af[r] = *(const short8*)&Als[(wr * 64 + r * 16 + lr) * 32 + co];
#pragma unroll
    for (int c4 = 0; c4 < 4; c4++)
      bfr[c4] = *(const short8*)&Bls[(wc * 64 + c4 * 16 + lr) * 32 + co];
#pragma unroll
    for (int r = 0; r < 4; r++)
#pragma unroll
      for (int c4 = 0; c4 < 4; c4++)
        acc[r][c4] = __builtin_amdgcn_mfma_f32_16x16x32_bf16(af[r], bfr[c4], acc[r][c4], 0, 0, 0);
  }
  int rbase = bm * 128 + wr * 64 + hi * 4;
  int cbase = bn * 128 + wc * 64 + lr;
#pragma unroll
  for (int r = 0; r < 4; r++) {
#pragma unroll
    for (int c4 = 0; c4 < 4; c4++) {
      int cc = cbase + c4 * 16;
      float bv = bias[cc];
#pragma unroll
      for (int j = 0; j < 4; j++) {
        int rr = rbase + r * 16 + j;
        C[(size_t)rr * OROW_US + GTAIL_US + cc] = f2bf(acc[r][c4][j] + bv);
      }
    }
  }
}

// ---------------- MEGA: rec (256 blocks, setprio 2) + proj (768 blocks, prio 0) --------
// [0,128): layer 0  — d=blk>>6, jt8=blk&63, 8 j-cols, 2-gate-packed whh0 in LDS,
//          G0 (bf16) from d_out tails.
// [128,256): layer 1 — same shape; whh1 in LDS, wih1 read from global in the
//          pipelined x1 phase (off the recurrent chain).
// [256,1024): projection — static tiles ln = p + 768k over bm-major (bn<234),
//          gated per bm on agg1[2bm], agg1[2bm+1] >= 128.
// Tail panels (bn in [234,250), the G0 region): 1 tile each on blocks [0,512),
//          gated on agg1[63] >= 128 (l1 done => l0 done reading G0).
// All 1024 blocks resident (LDS 34.5KB x4 = 138KB, 64 VGPR, 16 waves/CU).
// s_setprio(2) on rec waves: protects the latency-critical chain from issue
// arbitration against 12 co-resident proj waves (the R12 regression mechanism).
#define LDWr 520    // 32 rows x (512+8)

__global__ __launch_bounds__(256, 4) void k_mega(
    const unsigned short* __restrict__ h0i,   // (2,B,H) bf16
    const unsigned short* __restrict__ h1i,   // (2,B,H) bf16
    const float* __restrict__ cell,           // (4,B,H) fp32
    const unsigned short* __restrict__ whh0,  // (2,2048,512) bf16
    const unsigned short* __restrict__ wih1,  // (2,2048,1024) bf16
    const unsigned short* __restrict__ whh1,  // (2,2048,512) bf16
    const float* __restrict__ b1s,            // (2,2048) fp32
    float* __restrict__ dout,                 // output + G0 tails
    const unsigned short* __restrict__ fcwb,  // (V,1024) bf16
    const float* __restrict__ fcb,            // (V,) fp32
    unsigned short* __restrict__ H0,          // (SB,1024) bf16
    unsigned short* __restrict__ O1,          // (SB,1024) bf16
    unsigned* __restrict__ sync) {
  __shared__ unsigned short SM[32 * LDWr];              // 33,280 B
  __shared__ __align__(16) unsigned short HS[64 * 8];   // publish staging
  unsigned* cnt0 = sync;
  unsigned* cnt1 = sync + 32768;
  unsigned* agg1 = sync + 65536;
  int tid = threadIdx.x;
  int w = tid >> 6, l = tid & 63;
  int lr = l & 15, hi = l >> 4;
  const unsigned short* G0u = (const unsigned short*)dout;

  // ---- shared projection-tile machinery (proj blocks + tail phase) ----
  int wr = w >> 1, wc = w & 1;
  int c0 = w * 128 + l;
  int row0 = c0 >> 2, ks0 = (((c0 & 3) ^ (row0 & 3)) * 8);
  int c1 = c0 + 64;
  int row1 = c1 >> 2, ks1 = (((c1 & 3) ^ (row1 & 3)) * 8);
  int co = ((hi ^ (lr & 3)) * 8);
  unsigned short* Als = SM;
  unsigned short* Bls = SM + 4096;
  auto tile = [&](int bm, int bn) {
    const unsigned short* Ab = O1 + (size_t)(bm * 128) * 1024;
    const unsigned short* Bb = fcwb + (size_t)(bn * 128) * 1024;
    unsigned short* AlsW = &Als[w * 1024];
    unsigned short* BlsW = &Bls[w * 1024];
    f32x4 acc[4][4] = {};
    for (int kk = 0; kk < 1024; kk += 32) {
      __syncthreads();
      gload_lds16(Ab + (size_t)row0 * 1024 + kk + ks0, AlsW);
      gload_lds16(Ab + (size_t)row1 * 1024 + kk + ks1, AlsW + 512);
      gload_lds16(Bb + (size_t)row0 * 1024 + kk + ks0, BlsW);
      gload_lds16(Bb + (size_t)row1 * 1024 + kk + ks1, BlsW + 512);
      __syncthreads();
      short8 af[4], bfr[4];
#pragma unroll
      for (int r = 0; r < 4; r++)
        af[r] = *(const short8*)&Als[(wr * 64 + r * 16 + lr) * 32 + co];
#pragma unroll
      for (int c4 = 0; c4 < 4; c4++)
        bfr[c4] = *(const short8*)&Bls[(wc * 64 + c4 * 16 + lr) * 32 + co];
#pragma unroll
      for (int r = 0; r < 4; r++)
#pragma unroll
        for (int c4 = 0; c4 < 4; c4++)
          acc[r][c4] = __builtin_amdgcn_mfma_f32_16x16x32_bf16(af[r], bfr[c4], acc[r][c4], 0, 0, 0);
    }
    int rbase = bm * 128 + wr * 64 + hi * 4;
    int cbase = bn * 128 + wc * 64 + lr;
#pragma unroll
    for (int r = 0; r < 4; r++) {
#pragma unroll
      for (int c4 = 0; c4 < 4; c4++) {
        int cc = cbase + c4 * 16;
        float bv = fcb[cc];
#pragma unroll
        for (int jx = 0; jx < 4; jx++) {
          int rr = rbase + r * 16 + jx;
          size_t orow = (size_t)((rr & 63) * 64 + (rr >> 6));
          __builtin_nontemporal_store(acc[r][c4][jx] + bv, &dout[orow * V_ + cc]);
        }
      }
    }
  };

  if (blockIdx.x < 256) {
    // ================= RECURRENCE (high wave priority) =================
    __builtin_amdgcn_s_setprio(2);
    bool isL0 = blockIdx.x < 128;
    int idx = isL0 ? blockIdx.x : blockIdx.x - 128;
    int d = idx >> 6, jt8 = idx & 63;
    int j0 = jt8 * 8;
    const unsigned short* Wd = (isL0 ? whh0 : whh1) + (size_t)d * (G4 * H_);
    for (int c = tid; c < 32 * 64; c += 256) {
      int r = c >> 6, ck = c & 63;
      int g = r >> 3, jc = r & 7;
      *(int4*)&SM[r * LDWr + ck * 8] =
          *(const int4*)&Wd[(size_t)(g * H_ + j0 + jc) * H_ + ck * 8];
    }
    int j = j0 + (lr & 7);
    int b0 = w * 16 + hi * 4;
    f32x4 creg = {};
    if (lr < 8) {
      const float* cd = cell + (size_t)((isL0 ? 0 : 2) + d) * (B_ * H_);
#pragma unroll
      for (int jj = 0; jj < 4; jj++) creg[jj] = cd[(size_t)(b0 + jj) * H_ + j];
    }
    __syncthreads();

    if (isL0) {
      float gv[4][4];
      auto preloadG = [&](int t) {
#pragma unroll
        for (int jj = 0; jj < 4; jj++) {
          const unsigned short* Gb =
              G0u + (size_t)(t * B_ + b0 + jj) * OROW_US + GTAIL_US + d * 2048 + j;
#pragma unroll
          for (int g = 0; g < 4; g++) gv[g][jj] = bf2f(Gb[g * 512]);
        }
      };
      preloadG(0);
      for (int t = 0; t < S_; ++t) {
        if (t >= 1) {
          if (tid < 4) spin_ge(&cnt0[CIDX(t - 1, d, tid)], 16);
          __syncthreads();
        }
        const unsigned short* hp = (t == 0) ? h0i + (size_t)d * (B_ * H_)
                                            : H0 + (size_t)(t - 1) * B_ * 1024 + d * 512;
        size_t hstr = (t == 0) ? (size_t)H_ : 1024;
        const unsigned short* arow = hp + (size_t)(w * 16 + lr) * hstr + hi * 8;
        f32x4 acc0 = {}, acc1 = {};
#pragma unroll
        for (int ki = 0; ki < 16; ki++) {
          short8 a = *(const short8*)&arow[ki * 32];
          short8 bA = *(const short8*)&SM[lr * LDWr + ki * 32 + hi * 8];
          short8 bB = *(const short8*)&SM[(16 + lr) * LDWr + ki * 32 + hi * 8];
          acc0 = __builtin_amdgcn_mfma_f32_16x16x32_bf16(a, bA, acc0, 0, 0, 0);
          acc1 = __builtin_amdgcn_mfma_f32_16x16x32_bf16(a, bB, acc1, 0, 0, 0);
        }
        float pf[4], po[4];
#pragma unroll
        for (int jj = 0; jj < 4; jj++) {
          pf[jj] = __shfl_xor(acc0[jj], 8);
          po[jj] = __shfl_xor(acc1[jj], 8);
        }
        if (lr < 8) {
#pragma unroll
          for (int jj = 0; jj < 4; jj++) {
            float gi = acc0[jj] + gv[0][jj];
            float gf = pf[jj] + gv[1][jj];
            float gg = acc1[jj] + gv[2][jj];
            float go = po[jj] + gv[3][jj];
            float c = sigm(gf) * creg[jj] + sigm(gi) * tanhf(gg);
            creg[jj] = c;
            HS[(b0 + jj) * 8 + lr] = f2bf(sigm(go) * tanhf(c));
          }
        }
        __syncthreads();
        unsigned short* Ho = H0 + (size_t)t * B_ * 1024 + d * 512 + j0;
        if (tid < 64) st128_sys(&Ho[(size_t)tid * 1024], *(const i32x4*)&HS[tid * 8]);
        wait_vm0();
        __syncthreads();
        if (tid == 0) arrive(&cnt0[CIDX(t, d, jt8 & 3)]);
        if (t + 1 < S_) preloadG(t + 1);
      }
    } else {
      // layer 1: whh in LDS; wih1 gates computed from GLOBAL in pipelined x1 phase
      const float* b1d = b1s + d * G4;
      float bi_ = b1d[j], bf_ = b1d[512 + j], bg_ = b1d[1024 + j], bo_ = b1d[1536 + j];
      const unsigned short* Wg0 = wih1 + (size_t)d * (G4 * 1024) +
          (size_t)((lr >> 3) * H_ + j0 + (lr & 7)) * 1024 + hi * 8;
      const unsigned short* Wg1 = wih1 + (size_t)d * (G4 * 1024) +
          (size_t)((2 + (lr >> 3)) * H_ + j0 + (lr & 7)) * 1024 + hi * 8;
      f32x4 acc0, acc1;
      auto x1phase = [&](int t) {
        if (tid < 8) spin_ge(&cnt0[CIDX(t, 0, 0) + tid * 64], 16);
        __syncthreads();
        acc0 = (f32x4){}; acc1 = (f32x4){};
        const unsigned short* x1row = H0 + ((size_t)t * B_ + w * 16 + lr) * 1024 + hi * 8;
#pragma unroll 8
        for (int ki = 0; ki < 32; ki++) {
          short8 a = *(const short8*)&x1row[ki * 32];
          short8 bA = *(const short8*)&Wg0[ki * 32];
          short8 bB = *(const short8*)&Wg1[ki * 32];
          acc0 = __builtin_amdgcn_mfma_f32_16x16x32_bf16(a, bA, acc0, 0, 0, 0);
          acc1 = __builtin_amdgcn_mfma_f32_16x16x32_bf16(a, bB, acc1, 0, 0, 0);
        }
      };
      x1phase(0);
      for (int t = 0; t < S_; ++t) {
        if (t >= 1) {
          if (tid < 4) spin_ge(&cnt1[CIDX(t - 1, d, tid)], 16);
          __syncthreads();
        }
        const unsigned short* hprev = (t == 0)
            ? h1i + (size_t)d * (B_ * H_) + (size_t)(w * 16 + lr) * H_ + hi * 8
            : O1 + ((size_t)(t - 1) * B_ + w * 16 + lr) * 1024 + d * 512 + hi * 8;
#pragma unroll
        for (int ki = 0; ki < 16; ki++) {
          short8 a = *(const short8*)&hprev[ki * 32];
          short8 bA = *(const short8*)&SM[lr * LDWr + ki * 32 + hi * 8];
          short8 bB = *(const short8*)&SM[(16 + lr) * LDWr + ki * 32 + hi * 8];
          acc0 = __builtin_amdgcn_mfma_f32_16x16x32_bf16(a, bA, acc0, 0, 0, 0);
          acc1 = __builtin_amdgcn_mfma_f32_16x16x32_bf16(a, bB, acc1, 0, 0, 0);
        }
        float pf[4], po[4];
#pragma unroll
        for (int jj = 0; jj < 4; jj++) {
          pf[jj] = __shfl_xor(acc0[jj], 8);
          po[jj] = __shfl_xor(acc1[jj], 8);
        }
        if (lr < 8) {
#pragma unroll
          for (int jj = 0; jj < 4; jj++) {
            float gi = acc0[jj] + bi_;
            float gf = pf[jj] + bf_;
            float gg = acc1[jj] + bg_;
            float go = po[jj] + bo_;
            float c = sigm(gf) * creg[jj] + sigm(gi) * tanhf(gg);
            creg[jj] = c;
            HS[(b0 + jj) * 8 + lr] = f2bf(sigm(go) * tanhf(c));
          }
        }
        __syncthreads();
        unsigned short* Oo = O1 + (size_t)t * B_ * 1024 + d * 512 + j0;
        if (tid < 64) st128_sys(&Oo[(size_t)tid * 1024], *(const i32x4*)&HS[tid * 8]);
        wait_vm0();
        __syncthreads();
        if (tid == 0) arrive(&cnt1[CIDX(t, d, jt8 & 3)]);
        if (tid == 64) arrive(&agg1[t * 16]);
        if (t + 1 < S_) x1phase(t + 1);
      }
    }
    __builtin_amdgcn_s_setprio(0);   // drop priority before tail tiles
  } else {
    // ================= PROJECTION (768 blocks, static, frontier-gated) ==========
    int p = blockIdx.x - 256;
    for (int ln = p; ln < 7488; ln += 768) {
      int bm = ln / 234, bn = ln - bm * 234;
      if (tid < 2) spin_ge_slow(&agg1[(2 * bm + tid) * 16], 128);
      __syncthreads();
      tile(bm, bn);
    }
  }

  // ---- tail panels (G0-tail region, bn in [234,250)): blocks [0,512), 1 each ----
  if (blockIdx.x < 512) {
    if (tid == 0) spin_ge_slow(&agg1[63 * 16], 128);
    __syncthreads();
    int ln = blockIdx.x;
    tile(ln >> 4, 234 + (ln & 15));
  }
}

extern "C" void kernel_launch(void* const* d_in, const int* in_sizes, int n_in,
                              void* d_out, int out_size, void* d_ws, size_t ws_size,
                              hipStream_t stream) {
  const float* hidden = (const float*)d_in[0];
  const float* cell   = (const float*)d_in[1];
  const int*   Y      = (const int*)d_in[2];
  const float* emb    = (const float*)d_in[3];
  const float* wih0   = (const float*)d_in[4];
  const float* whh0   = (const float*)d_in[5];
  const float* bih0   = (const float*)d_in[6];
  const float* bhh0   = (const float*)d_in[7];
  const float* wih1   = (const float*)d_in[8];
  const float* whh1   = (const float*)d_in[9];
  const float* bih1   = (const float*)d_in[10];
  const float* bhh1   = (const float*)d_in[11];
  const float* fcw    = (const float*)d_in[12];
  const float* fcb    = (const float*)d_in[13];

  char* ws = (char*)d_ws;
  size_t off = 0;
  auto alloc = [&](size_t bytes) {
    void* p = ws + off;
    off += (bytes + 255) & ~(size_t)255;
    return p;
  };
  unsigned short* wih0b = (unsigned short*)alloc((size_t)2 * G4 * E_ * 2);
  unsigned short* whh0b = (unsigned short*)alloc((size_t)2 * G4 * H_ * 2);
  unsigned short* wih1b = (unsigned short*)alloc((size_t)2 * G4 * 1024 * 2);
  unsigned short* whh1b = (unsigned short*)alloc((size_t)2 * G4 * H_ * 2);
  unsigned short* fcwb  = (unsigned short*)alloc((size_t)V_ * 1024 * 2);
  unsigned short* Xb    = (unsigned short*)alloc((size_t)SB * E_ * 2);
  unsigned short* H0    = (unsigned short*)alloc((size_t)SB * 1024 * 2);
  unsigned short* O1    = (unsigned short*)alloc((size_t)SB * 1024 * 2);
  unsigned short* h0i   = (unsigned short*)alloc((size_t)2 * B_ * H_ * 2);
  unsigned short* h1i   = (unsigned short*)alloc((size_t)2 * B_ * H_ * 2);
  float* b0s = (float*)alloc((size_t)2 * G4 * 4);
  float* b1s = (float*)alloc((size_t)2 * G4 * 4);
  unsigned* syncbuf = (unsigned*)alloc((size_t)SYNC_UINTS * 4);
  (void)ws_size;

  // --- prep ---
  k_f2bf<<<2048, 256, 0, stream>>>(wih0, wih0b, 2 * G4 * E_);
  k_f2bf<<<2048, 256, 0, stream>>>(whh0, whh0b, 2 * G4 * H_);
  k_f2bf<<<2048, 256, 0, stream>>>(wih1, wih1b, 2 * G4 * 1024);
  k_f2bf<<<2048, 256, 0, stream>>>(whh1, whh1b, 2 * G4 * H_);
  k_f2bf<<<4096, 256, 0, stream>>>(fcw, fcwb, V_ * 1024);
  k_addbias<<<16, 256, 0, stream>>>(bih0, bhh0, b0s, 2 * G4);
  k_addbias<<<16, 256, 0, stream>>>(bih1, bhh1, b1s, 2 * G4);
  k_gather<<<SB, 256, 0, stream>>>(Y, emb, Xb);
  k_init_h<<<512, 256, 0, stream>>>(hidden, h0i, h1i);
  (void)hipMemsetAsync(syncbuf, 0, (size_t)SYNC_UINTS * 4, stream);

  // --- layer-0 input gates -> bf16 G0 in d_out row tails ---
  k_gemm_g0<<<1024, 256, 0, stream>>>(Xb, wih0b, b0s, (unsigned short*)d_out,
                                      E_, SB / 128, 1024);

  // --- mega: recurrence (prio 2) + co-resident projection (prio 0) ---
  k_mega<<<1024, 256, 0, stream>>>(h0i, h1i, cell, whh0b, wih1b, whh1b, b1s,
                                   (float*)d_out, fcwb, fcb, H0, O1, syncbuf);
}